// Round 7
// baseline (460.904 us; speedup 1.0000x reference)
//
#include <hip/hip_runtime.h>
#include <math.h>

#define B 4
#define T1 16
#define T2 16
#define SEG 4
#define V 8000
#define E 256
#define H 256
#define ENC 512
#define EOS 2
#define NEGV -1e30f
#define G4 1024
#define NCELL 1088
#define T21 17
#define NL 272        // 17*16 lstm tiles per layer-step
#define TPS 2125      // 17*125 fc tiles per step
#define MROWS 5440    // 5*1088 batched fc rows

typedef __attribute__((ext_vector_type(4))) float f32x4;
typedef __attribute__((ext_vector_type(8))) short bf16x8;

__device__ __forceinline__ float sigm(float x) { return 1.f / (1.f + __expf(-x)); }
__device__ __forceinline__ float ftanh(float x) { float e = __expf(2.f * x); return 1.f - 2.f / (e + 1.f); }
__device__ __forceinline__ float b2f(short x) {
    unsigned u = ((unsigned)(unsigned short)x) << 16;
    return __builtin_bit_cast(float, u);
}
__device__ __forceinline__ short f2b(float f) {
    unsigned u = __builtin_bit_cast(unsigned, f);
    unsigned r = (u + 0x7fffu + ((u >> 16) & 1u)) >> 16;
    return (short)r;
}

// batched-load GEMM core: 64Mx16N per wave, K = KH*128, all loads of a K-half
// issued as one batch (2 latency exposures for K=256) before the MFMAs.
template<int KH>
__device__ __forceinline__ void gemm_acc(const short* __restrict__ Ap, int lda,
                                         const short* __restrict__ Bp, f32x4 acc[4]) {
#pragma unroll
    for (int kh = 0; kh < KH; ++kh) {
        bf16x8 a[4][4], b[4];
#pragma unroll
        for (int kk = 0; kk < 4; ++kk) {
            int k = kh * 128 + kk * 32;
            b[kk] = *(const bf16x8*)(Bp + k);
#pragma unroll
            for (int mf = 0; mf < 4; ++mf)
                a[mf][kk] = *(const bf16x8*)(Ap + (size_t)mf * 16 * lda + k);
        }
#pragma unroll
        for (int kk = 0; kk < 4; ++kk)
#pragma unroll
            for (int mf = 0; mf < 4; ++mf)
                acc[mf] = __builtin_amdgcn_mfma_f32_16x16x32_bf16(a[mf][kk], b[kk], acc[mf], 0, 0, 0);
    }
}

// ---------------- fused setup ----------------
__global__ void k_setup(const float* __restrict__ fcw, const float* __restrict__ whh0,
                        const float* __restrict__ wih1, const float* __restrict__ whh1,
                        const float* __restrict__ phw, const float* __restrict__ pcw,
                        const float* __restrict__ wih0, const float* __restrict__ b1,
                        short* __restrict__ fcwbf, short* __restrict__ whh0i, short* __restrict__ w1i,
                        float* __restrict__ projhT, float* __restrict__ projcT,
                        float* __restrict__ ctxT, float* __restrict__ xT, float* __restrict__ b1i) {
    int bid = blockIdx.x, tid = threadIdx.x;
    if (bid < 8000) { int i = bid * 256 + tid; fcwbf[i] = f2b(fcw[i]); return; }
    bid -= 8000;
    if (bid < 1024) {
        int i = bid * 256 + tid; int gp = i >> 8, k = i & 255; int j = gp >> 2, gate = gp & 3;
        whh0i[i] = f2b(whh0[(size_t)(gate * 256 + j) * 256 + k]); return;
    }
    bid -= 1024;
    if (bid < 2048) {
        int i = bid * 256 + tid; int gp = i >> 9, k = i & 511; int j = gp >> 2, gate = gp & 3;
        float v = (k < 256) ? wih1[(size_t)(gate * 256 + j) * 256 + k]
                            : whh1[(size_t)(gate * 256 + j) * 256 + (k - 256)];
        w1i[i] = f2b(v); return;
    }
    bid -= 2048;
    if (bid < 512) { int i = bid * 256 + tid; int k = i >> 8, r = i & 255; projhT[i] = phw[(size_t)r * ENC + k]; return; }
    bid -= 512;
    if (bid < 512) { int i = bid * 256 + tid; int k = i >> 8, r = i & 255; projcT[i] = pcw[(size_t)r * ENC + k]; return; }
    bid -= 512;
    if (bid < 2048) {
        int i = bid * 256 + tid; int g = i >> 9, k = i & 511; float v = wih0[i];
        if (k < 256) ctxT[(size_t)k * G4 + g] = v; else xT[(size_t)(k - 256) * G4 + g] = v;
        return;
    }
    bid -= 2048;
    if (bid < 4) { int i = bid * 256 + tid; int j = i >> 2, gate = i & 3; b1i[i] = b1[gate * 256 + j]; return; }
}

// ---------------- h0/c0 ----------------
__global__ void k_init_state(const float* __restrict__ enc, const float* __restrict__ phT,
                             const float* __restrict__ phb, const float* __restrict__ pcT,
                             const float* __restrict__ pcb, float* __restrict__ h0, float* __restrict__ c0) {
    __shared__ float eo[ENC];
    int bi = blockIdx.x;
    int b = bi / T1, i = bi % T1;
    int j = threadIdx.x;
    for (int e = j; e < ENC; e += 256) eo[e] = enc[(size_t)(i * B + b) * ENC + e];
    __syncthreads();
    float ha = phb[j], ca = pcb[j];
    for (int e = 0; e < ENC; ++e) {
        float x = eo[e];
        ha += x * phT[(size_t)e * H + j];
        ca += x * pcT[(size_t)e * H + j];
    }
    h0[(size_t)bi * H + j] = ha;
    c0[(size_t)bi * H + j] = ca;
}

// ---------------- fused init ----------------
__global__ void k_init2(const int* __restrict__ y, const float* __restrict__ embed, const float* __restrict__ se,
                        const float* __restrict__ h0, const float* __restrict__ c0,
                        const float* __restrict__ ctxT, const float* __restrict__ xT,
                        const float* __restrict__ b0,
                        float* __restrict__ c1, float* __restrict__ c2,
                        short* __restrict__ hc0, short* __restrict__ h2slab0,
                        float* __restrict__ pre_ctxi, float* __restrict__ pre_xi) {
    __shared__ float sb[256];
    int bid = blockIdx.x, j = threadIdx.x;
    if (bid < NCELL) {
        int cell = bid, bi = cell / T21;
        c1[(size_t)cell * H + j] = c0[(size_t)bi * H + j];
        c2[(size_t)cell * H + j] = 0.f;
        hc0[(size_t)cell * 512 + j] = f2b(h0[(size_t)bi * H + j]);
        h2slab0[(size_t)cell * 256 + j] = 0;
        return;
    }
    bid -= NCELL;
    if (bid < 64) {
        int bi = bid;
        sb[j] = h0[(size_t)bi * H + j];
        __syncthreads();
        float a0 = b0[j], a1 = b0[256 + j], a2 = b0[512 + j], a3 = b0[768 + j];
        for (int k = 0; k < H; ++k) {
            float x = sb[k];
            const float* w = ctxT + (size_t)k * G4;
            a0 += x * w[j]; a1 += x * w[256 + j]; a2 += x * w[512 + j]; a3 += x * w[768 + j];
        }
        *(float4*)&pre_ctxi[(size_t)bi * G4 + 4 * j] = make_float4(a0, a1, a2, a3);
        return;
    }
    bid -= 64;
    int row = bid;                    // (s*B + b)*T21 + t
    int s = row / (B * T21), rem = row % (B * T21);
    int b = rem / T21, t = rem % T21;
    const float* src;
    if (s == 0) src = se;
    else { int tt = t + s - 1; if (tt > 15) tt = 15; src = embed + (size_t)y[b * T2 + tt] * E; }
    sb[j] = src[j];
    __syncthreads();
    float a0 = 0, a1 = 0, a2 = 0, a3 = 0;
    for (int k = 0; k < E; ++k) {
        float x = sb[k];
        const float* w = xT + (size_t)k * G4;
        a0 += x * w[j]; a1 += x * w[256 + j]; a2 += x * w[512 + j]; a3 += x * w[768 + j];
    }
    *(float4*)&pre_xi[(size_t)row * G4 + 4 * j] = make_float4(a0, a1, a2, a3);
}

// ---------------- lstm tile: 64Mx64N, 4 waves n-split, fused nonlinearity ----------------
template<int LAYER>
__device__ __forceinline__ void lstm_body(int s, int l, float* smem,
        const short* __restrict__ A, const short* __restrict__ Bw,
        const float* __restrict__ pre_ctxi, const float* __restrict__ pre_xi,
        const float* __restrict__ b1i, float* __restrict__ cst,
        short* __restrict__ OUT, const short* __restrict__ h2old, short* __restrict__ h2new) {
    constexpr int K = LAYER ? 512 : 256;
    int tid = threadIdx.x;
    int wave = tid >> 6, lane = tid & 63, ln = lane & 15, kg = lane >> 4;
    int mb = l >> 4, nb = l & 15;
    int m0 = mb * 64, n0 = nb * 64;
    const short* Ap = A + (size_t)(m0 + ln) * 512 + kg * 8;
    const short* Bp = Bw + (size_t)(n0 + wave * 16 + ln) * K + kg * 8;
    f32x4 acc[4] = {};
    gemm_acc<LAYER ? 4 : 2>(Ap, 512, Bp, acc);
#pragma unroll
    for (int mf = 0; mf < 4; ++mf)
#pragma unroll
        for (int r = 0; r < 4; ++r)
            smem[(mf * 16 + kg * 4 + r) * 68 + wave * 16 + ln] = acc[mf][r];
    __syncthreads();
    int jlo = nb * 16;
#pragma unroll
    for (int q = 0; q < 4; ++q) {
        int item = q * 256 + tid;
        int c = item >> 4, jj = item & 15;
        int cell = m0 + c;
        int j = jlo + jj;
        float4 g = *(float4*)&smem[c * 68 + 4 * jj];
        float ig, fg, gg, og;
        if constexpr (LAYER == 0) {
            int bi = cell / T21;
            int bb = bi >> 4;
            int t = cell % T21;
            int prow = (s * B + bb) * T21 + t;
            float4 pc = *(const float4*)&pre_ctxi[(size_t)bi * G4 + 4 * j];
            float4 px = *(const float4*)&pre_xi[(size_t)prow * G4 + 4 * j];
            ig = g.x + pc.x + px.x; fg = g.y + pc.y + px.y;
            gg = g.z + pc.z + px.z; og = g.w + pc.w + px.w;
        } else {
            float4 bv = *(const float4*)&b1i[4 * j];
            ig = g.x + bv.x; fg = g.y + bv.y; gg = g.z + bv.z; og = g.w + bv.w;
        }
        float cold = cst[(size_t)cell * H + j];
        float cn = sigm(fg) * cold + sigm(ig) * ftanh(gg);
        float hn = sigm(og) * ftanh(cn);
        cst[(size_t)cell * H + j] = cn;
        if constexpr (LAYER == 0) {
            OUT[(size_t)cell * 512 + j] = f2b(hn);
            OUT[(size_t)cell * 512 + 256 + j] = h2old[(size_t)cell * 256 + j];
        } else {
            h2new[(size_t)cell * 256 + j] = f2b(hn);
        }
    }
}

// ---------------- fc tile (batched over steps): 64Mx64N, max-free exp-sum -> psum ----------------
__device__ __forceinline__ void fc_body(int t, float* smem,
        const short* __restrict__ Abase, const short* __restrict__ Wv,
        const float* __restrict__ fcb, float* __restrict__ psum) {
    int tid = threadIdx.x;
    int wave = tid >> 6, lane = tid & 63, ln = lane & 15, kg = lane >> 4;
    int s = t / TPS; int r = t - s * TPS;
    int nb = r / 17, mb = r - nb * 17;
    int m0 = s * NCELL + mb * 64;       // global batched row
    int n0 = nb * 64;
    const short* Ap = Abase + (size_t)(m0 + ln) * 256 + kg * 8;
    const short* Bp = Wv + (size_t)(n0 + wave * 16 + ln) * 256 + kg * 8;
    f32x4 acc[4] = {};
    gemm_acc<2>(Ap, 256, Bp, acc);
    float fbn = fcb[n0 + wave * 16 + ln];
    float sums[4][4];
#pragma unroll
    for (int mf = 0; mf < 4; ++mf)
#pragma unroll
        for (int rr = 0; rr < 4; ++rr)
            sums[mf][rr] = __expf(acc[mf][rr] + fbn);
#pragma unroll
    for (int mask = 1; mask < 16; mask <<= 1)
#pragma unroll
        for (int mf = 0; mf < 4; ++mf)
#pragma unroll
            for (int rr = 0; rr < 4; ++rr)
                sums[mf][rr] += __shfl_xor(sums[mf][rr], mask);
    if (ln == 0) {
#pragma unroll
        for (int mf = 0; mf < 4; ++mf)
#pragma unroll
            for (int rr = 0; rr < 4; ++rr)
                smem[wave * 64 + mf * 16 + kg * 4 + rr] = sums[mf][rr];
    }
    __syncthreads();
    if (tid < 64) {
        float v = smem[tid] + smem[64 + tid] + smem[128 + tid] + smem[192 + tid];
        psum[(size_t)nb * MROWS + m0 + tid] = v;
    }
}

// ---------------- combine: tgt/EOS dots + sum of 125 psum partials ----------------
__device__ __forceinline__ void combine_body(int cb,
        const short* __restrict__ h2all, const short* __restrict__ Wv,
        const float* __restrict__ fcb, const int* __restrict__ y,
        const float* __restrict__ psum, float* __restrict__ sel, float* __restrict__ eosp) {
    int s = cb / 17, blk = cb % 17;
    int tid = threadIdx.x;
    int cl = tid >> 2, q = tid & 3;
    int cell = blk * 64 + cl;
    int b = cell / (T1 * T21);
    int t = cell % T21;
    int tv = 0;
    if (s < SEG) { int tt = t + s; if (tt > 15) tt = 15; tv = y[b * T2 + tt]; }
    const short* hp = h2all + (size_t)(s + 1) * NCELL * 256 + (size_t)cell * 256 + q * 64;
    const short* w1 = Wv + (size_t)tv * 256 + q * 64;
    const short* w2 = Wv + (size_t)EOS * 256 + q * 64;
    float d1 = 0.f, d2 = 0.f;
#pragma unroll
    for (int u = 0; u < 8; ++u) {
        bf16x8 av  = *(const bf16x8*)(hp + u * 8);
        bf16x8 wv1 = *(const bf16x8*)(w1 + u * 8);
        bf16x8 wv2 = *(const bf16x8*)(w2 + u * 8);
#pragma unroll
        for (int e = 0; e < 8; ++e) {
            float a = b2f(av[e]);
            d1 += a * b2f(wv1[e]);
            d2 += a * b2f(wv2[e]);
        }
    }
    d1 += __shfl_xor(d1, 1); d1 += __shfl_xor(d1, 2);
    d2 += __shfl_xor(d2, 1); d2 += __shfl_xor(d2, 2);
    int col = s * NCELL + cell;
    float ss = 0.f;
    for (int v2 = q * 32; v2 < q * 32 + 32 && v2 < 125; ++v2)
        ss += psum[(size_t)v2 * MROWS + col];
    ss += __shfl_xor(ss, 1); ss += __shfl_xor(ss, 2);
    if (q == 0) {
        float lse = __logf(ss);
        sel[s * NCELL + cell]  = d1 + fcb[tv]  - lse;
        eosp[s * NCELL + cell] = d2 + fcb[EOS] - lse;
    }
}

// ---------------- merged pipeline dispatch: [lstm | fc slice | combine] ----------------
__global__ void k_step(int layer, int s_l, int nlstm, int fc_lo, int fc_n, int cmb_lo, int cmb_n,
        const short* __restrict__ hcin, const short* __restrict__ whh0i, const short* __restrict__ w1i,
        const float* __restrict__ pre_ctxi, const float* __restrict__ pre_xi, const float* __restrict__ b1i,
        float* __restrict__ c1, float* __restrict__ c2,
        short* __restrict__ hcout, short* __restrict__ h2all,
        const short* __restrict__ fcwbf, const float* __restrict__ fcb, const int* __restrict__ y,
        float* __restrict__ psum, float* __restrict__ sel, float* __restrict__ eosp) {
    __shared__ float smem[64 * 68];
    int bx = blockIdx.x;
    if (bx < nlstm) {
        if (layer == 0)
            lstm_body<0>(s_l, bx, smem, hcin, whh0i, pre_ctxi, pre_xi, nullptr, c1,
                         hcout, h2all + (size_t)s_l * NCELL * 256, nullptr);
        else
            lstm_body<1>(s_l, bx, smem, hcin, w1i, nullptr, nullptr, b1i, c2,
                         nullptr, nullptr, h2all + (size_t)(s_l + 1) * NCELL * 256);
        return;
    }
    bx -= nlstm;
    if (bx < fc_n) {
        // bijective chunked XCD swizzle within the slice (nb-major tile order)
        int qq = fc_n >> 3, rr = fc_n & 7;
        int x = bx & 7, j = bx >> 3;
        int tl = x * qq + (x < rr ? x : rr) + j;
        fc_body(fc_lo + tl, smem, h2all + (size_t)NCELL * 256, fcwbf, fcb, psum);
        return;
    }
    bx -= fc_n;
    if (bx < cmb_n)
        combine_body(cmb_lo + bx, h2all, fcwbf, fcb, y, psum, sel, eosp);
}

// ---------------- final DP, fully LDS-resident ----------------
__global__ void k_dp(const float* __restrict__ sel, const float* __restrict__ eosp, float* __restrict__ out) {
    __shared__ float row[SEG + 1][NCELL];
    __shared__ float alpha[B][T21];
    int tid = threadIdx.x;
    for (int c = tid; c < NCELL; c += 256) {
        float cum = 0.f;
        row[0][c] = eosp[c];
#pragma unroll
        for (int j = 1; j <= SEG; ++j) {
            cum += sel[(j - 1) * NCELL + c];
            row[j][c] = cum + eosp[j * NCELL + c];
        }
    }
    int b = tid / T21, t = tid % T21;
    bool act = tid < B * T21;
    if (act) alpha[b][t] = (t == 0) ? 0.f : NEGV;
    __syncthreads();
    for (int i = 0; i < T1; ++i) {
        float val = NEGV;
        if (act) {
            float terms[SEG + 1];
            float mx = -3.4e38f;
            int cnt2 = 0;
            for (int j = 0; j <= SEG && j <= t; ++j) {
                int cell = (b * T1 + i) * T21 + (t - j);
                float term = alpha[b][t - j] + row[j][cell];
                terms[cnt2++] = term;
                mx = fmaxf(mx, term);
            }
            float ssum = 0.f;
            for (int k2 = 0; k2 < cnt2; ++k2) ssum += __expf(terms[k2] - mx);
            val = mx + __logf(ssum);
        }
        __syncthreads();
        if (act) alpha[b][t] = val;
        __syncthreads();
    }
    if (act && t == T2) out[b] = alpha[b][T2];
}

extern "C" void kernel_launch(void* const* d_in, const int* in_sizes, int n_in,
                              void* d_out, int out_size, void* d_ws, size_t ws_size,
                              hipStream_t stream) {
    const int*   y     = (const int*)d_in[0];
    const float* enc   = (const float*)d_in[1];
    const float* embed = (const float*)d_in[2];
    const float* se    = (const float*)d_in[3];
    const float* phw   = (const float*)d_in[4];
    const float* phb   = (const float*)d_in[5];
    const float* pcw   = (const float*)d_in[6];
    const float* pcb   = (const float*)d_in[7];
    const float* wih0  = (const float*)d_in[8];
    const float* whh0  = (const float*)d_in[9];
    const float* b0    = (const float*)d_in[10];
    const float* wih1  = (const float*)d_in[11];
    const float* whh1  = (const float*)d_in[12];
    const float* b1    = (const float*)d_in[13];
    const float* fcw   = (const float*)d_in[14];
    const float* fcb   = (const float*)d_in[15];

    float* ws = (float*)d_ws;
    size_t off = 0;
    auto alloc = [&](size_t n) { float* p = ws + off; off += n; return p; };
    float* projhT   = alloc((size_t)ENC * H);
    float* projcT   = alloc((size_t)ENC * H);
    float* ctxT     = alloc((size_t)H * G4);
    float* xT       = alloc((size_t)E * G4);
    float* h0       = alloc((size_t)B * T1 * H);
    float* c0       = alloc((size_t)B * T1 * H);
    float* pre_ctxi = alloc((size_t)B * T1 * G4);
    float* pre_xi   = alloc((size_t)(SEG + 1) * B * T21 * G4);
    float* c1       = alloc((size_t)NCELL * H);
    float* c2       = alloc((size_t)NCELL * H);
    float* b1i      = alloc((size_t)G4);
    float* selbuf   = alloc((size_t)(SEG + 1) * NCELL);
    float* eospbuf  = alloc((size_t)(SEG + 1) * NCELL);
    float* psum     = alloc((size_t)125 * MROWS);
    short* hc0      = (short*)alloc((size_t)NCELL * 512 / 2);
    short* hc1      = (short*)alloc((size_t)NCELL * 512 / 2);
    short* h2all    = (short*)alloc((size_t)6 * NCELL * 256 / 2);
    short* whh0i    = (short*)alloc((size_t)G4 * 256 / 2);
    short* w1i      = (short*)alloc((size_t)G4 * 512 / 2);
    short* fcwbf    = (short*)alloc((size_t)V * H / 2);

    short* hcb[2] = { hc0, hc1 };

    hipLaunchKernelGGL(k_setup, dim3(14148), dim3(256), 0, stream,
                       fcw, whh0, wih1, whh1, phw, pcw, wih0, b1,
                       fcwbf, whh0i, w1i, projhT, projcT, ctxT, xT, b1i);
    hipLaunchKernelGGL(k_init_state, dim3(B * T1), dim3(256), 0, stream,
                       enc, projhT, phb, projcT, pcb, h0, c0);
    hipLaunchKernelGGL(k_init2, dim3(NCELL + 64 + (SEG + 1) * B * T21), dim3(256), 0, stream,
                       y, embed, se, h0, c0, ctxT, xT, b0, c1, c2, hcb[0], h2all,
                       pre_ctxi, pre_xi);

    auto STEP = [&](int layer, int s_l, int nlstm, int fc_lo, int fc_n, int cmb_lo, int cmb_n) {
        const short* hcin = (layer == 0) ? hcb[s_l & 1] : hcb[(s_l + 1) & 1];
        short* hcout = hcb[(s_l + 1) & 1];
        hipLaunchKernelGGL(k_step, dim3(nlstm + fc_n + cmb_n), dim3(256), 0, stream,
                           layer, s_l, nlstm, fc_lo, fc_n, cmb_lo, cmb_n,
                           hcin, whh0i, w1i, pre_ctxi, pre_xi, b1i, c1, c2, hcout, h2all,
                           fcwbf, fcb, y, psum, selbuf, eospbuf);
    };

    STEP(0, 0, NL,    0,    0,  0,  0);   // L0_0
    STEP(1, 0, NL,    0,    0,  0,  0);   // L1_0
    STEP(0, 1, NL,    0, 1062,  0,  0);   // L0_1 | fc_0 a
    STEP(1, 1, NL, 1062, 1063,  0,  0);   // L1_1 | fc_0 b
    STEP(0, 2, NL, 2125, 1062,  0, 17);   // L0_2 | fc_1 a | cmb_0
    STEP(1, 2, NL, 3187, 1063,  0,  0);   // L1_2 | fc_1 b
    STEP(0, 3, NL, 4250, 1062, 17, 17);   // L0_3 | fc_2 a | cmb_1
    STEP(1, 3, NL, 5312, 1063,  0,  0);   // L1_3 | fc_2 b
    STEP(0, 4, NL, 6375, 1062, 34, 17);   // L0_4 | fc_3 a | cmb_2
    STEP(1, 4, NL, 7437, 1063,  0,  0);   // L1_4 | fc_3 b
    STEP(-1, 0, 0, 8500, 2125, 51, 17);   // fc_4 | cmb_3
    STEP(-1, 0, 0,    0,    0, 68, 17);   // cmb_4

    hipLaunchKernelGGL(k_dp, dim3(1), dim3(256), 0, stream, selbuf, eospbuf, (float*)d_out);
}

// Round 8
// 418.316 us; speedup vs baseline: 1.1018x; 1.1018x over previous
//
#include <hip/hip_runtime.h>
#include <math.h>

#define B 4
#define T1 16
#define T2 16
#define SEG 4
#define V 8000
#define E 256
#define H 256
#define ENC 512
#define EOS 2
#define NEGV -1e30f
#define G4 1024
#define NCELL 1088
#define T21 17
#define NL 272        // 17*16 lstm tiles per layer-step
#define MROWS 5440    // 5*1088 batched fc rows
#define NFCT 10625    // 5*17*125 fc tiles

typedef __attribute__((ext_vector_type(4))) float f32x4;
typedef __attribute__((ext_vector_type(8))) short bf16x8;

__device__ __forceinline__ float sigm(float x) { return 1.f / (1.f + __expf(-x)); }
__device__ __forceinline__ float ftanh(float x) { float e = __expf(2.f * x); return 1.f - 2.f / (e + 1.f); }
__device__ __forceinline__ float b2f(short x) {
    unsigned u = ((unsigned)(unsigned short)x) << 16;
    return __builtin_bit_cast(float, u);
}
__device__ __forceinline__ short f2b(float f) {
    unsigned u = __builtin_bit_cast(unsigned, f);
    unsigned r = (u + 0x7fffu + ((u >> 16) & 1u)) >> 16;
    return (short)r;
}

// GEMM core: 64Mx16N per wave, K = KH*128. All 20 loads of a K-half are issued
// BEFORE any MFMA of that half (sched_barrier fence keeps the batch intact;
// launch_bounds(256,2) gives the 256-VGPR budget to hold it).
template<int KH, int LDA>
__device__ __forceinline__ void gemm_acc(const short* __restrict__ Ap,
                                         const short* __restrict__ Bp, f32x4 acc[4]) {
#pragma unroll
    for (int kh = 0; kh < KH; ++kh) {
        bf16x8 a[4][4], b[4];
#pragma unroll
        for (int kk = 0; kk < 4; ++kk) {
            int k = kh * 128 + kk * 32;
            b[kk] = *(const bf16x8*)(Bp + k);
#pragma unroll
            for (int mf = 0; mf < 4; ++mf)
                a[mf][kk] = *(const bf16x8*)(Ap + (size_t)mf * 16 * LDA + k);
        }
        __builtin_amdgcn_sched_barrier(0);   // all loads of this half issued first
#pragma unroll
        for (int kk = 0; kk < 4; ++kk)
#pragma unroll
            for (int mf = 0; mf < 4; ++mf)
                acc[mf] = __builtin_amdgcn_mfma_f32_16x16x32_bf16(a[mf][kk], b[kk], acc[mf], 0, 0, 0);
    }
}

// ---------------- fused setup ----------------
__global__ void k_setup(const float* __restrict__ fcw, const float* __restrict__ whh0,
                        const float* __restrict__ wih1, const float* __restrict__ whh1,
                        const float* __restrict__ phw, const float* __restrict__ pcw,
                        const float* __restrict__ wih0, const float* __restrict__ b1,
                        short* __restrict__ fcwbf, short* __restrict__ whh0i, short* __restrict__ w1i,
                        float* __restrict__ projhT, float* __restrict__ projcT,
                        float* __restrict__ ctxT, float* __restrict__ xT, float* __restrict__ b1i) {
    int bid = blockIdx.x, tid = threadIdx.x;
    if (bid < 8000) { int i = bid * 256 + tid; fcwbf[i] = f2b(fcw[i]); return; }
    bid -= 8000;
    if (bid < 1024) {
        int i = bid * 256 + tid; int gp = i >> 8, k = i & 255; int j = gp >> 2, gate = gp & 3;
        whh0i[i] = f2b(whh0[(size_t)(gate * 256 + j) * 256 + k]); return;
    }
    bid -= 1024;
    if (bid < 2048) {
        int i = bid * 256 + tid; int gp = i >> 9, k = i & 511; int j = gp >> 2, gate = gp & 3;
        float v = (k < 256) ? wih1[(size_t)(gate * 256 + j) * 256 + k]
                            : whh1[(size_t)(gate * 256 + j) * 256 + (k - 256)];
        w1i[i] = f2b(v); return;
    }
    bid -= 2048;
    if (bid < 512) { int i = bid * 256 + tid; int k = i >> 8, r = i & 255; projhT[i] = phw[(size_t)r * ENC + k]; return; }
    bid -= 512;
    if (bid < 512) { int i = bid * 256 + tid; int k = i >> 8, r = i & 255; projcT[i] = pcw[(size_t)r * ENC + k]; return; }
    bid -= 512;
    if (bid < 2048) {
        int i = bid * 256 + tid; int g = i >> 9, k = i & 511; float v = wih0[i];
        if (k < 256) ctxT[(size_t)k * G4 + g] = v; else xT[(size_t)(k - 256) * G4 + g] = v;
        return;
    }
    bid -= 2048;
    if (bid < 4) { int i = bid * 256 + tid; int j = i >> 2, gate = i & 3; b1i[i] = b1[gate * 256 + j]; return; }
}

// ---------------- h0/c0 ----------------
__global__ void k_init_state(const float* __restrict__ enc, const float* __restrict__ phT,
                             const float* __restrict__ phb, const float* __restrict__ pcT,
                             const float* __restrict__ pcb, float* __restrict__ h0, float* __restrict__ c0) {
    __shared__ float eo[ENC];
    int bi = blockIdx.x;
    int b = bi / T1, i = bi % T1;
    int j = threadIdx.x;
    for (int e = j; e < ENC; e += 256) eo[e] = enc[(size_t)(i * B + b) * ENC + e];
    __syncthreads();
    float ha = phb[j], ca = pcb[j];
    for (int e = 0; e < ENC; ++e) {
        float x = eo[e];
        ha += x * phT[(size_t)e * H + j];
        ca += x * pcT[(size_t)e * H + j];
    }
    h0[(size_t)bi * H + j] = ha;
    c0[(size_t)bi * H + j] = ca;
}

// ---------------- fused init: H_{-1}=hcA cols0-255, H_0 upper half zero, states, pre_ctx, pre_x ----------------
__global__ void k_init2(const int* __restrict__ y, const float* __restrict__ embed, const float* __restrict__ se,
                        const float* __restrict__ h0, const float* __restrict__ c0,
                        const float* __restrict__ ctxT, const float* __restrict__ xT,
                        const float* __restrict__ b0,
                        float* __restrict__ c1, float* __restrict__ c2,
                        short* __restrict__ hcA, short* __restrict__ hcB,
                        float* __restrict__ pre_ctxi, float* __restrict__ pre_xi) {
    __shared__ float sb[256];
    int bid = blockIdx.x, j = threadIdx.x;
    if (bid < NCELL) {
        int cell = bid, bi = cell / T21;
        c1[(size_t)cell * H + j] = c0[(size_t)bi * H + j];
        c2[(size_t)cell * H + j] = 0.f;
        hcA[(size_t)cell * 512 + j] = f2b(h0[(size_t)bi * H + j]);  // h1_{-1}
        hcB[(size_t)cell * 512 + 256 + j] = 0;                      // h2_{-1}
        return;
    }
    bid -= NCELL;
    if (bid < 64) {
        int bi = bid;
        sb[j] = h0[(size_t)bi * H + j];
        __syncthreads();
        float a0 = b0[j], a1 = b0[256 + j], a2 = b0[512 + j], a3 = b0[768 + j];
        for (int k = 0; k < H; ++k) {
            float x = sb[k];
            const float* w = ctxT + (size_t)k * G4;
            a0 += x * w[j]; a1 += x * w[256 + j]; a2 += x * w[512 + j]; a3 += x * w[768 + j];
        }
        *(float4*)&pre_ctxi[(size_t)bi * G4 + 4 * j] = make_float4(a0, a1, a2, a3);
        return;
    }
    bid -= 64;
    int row = bid;                    // (s*B + b)*T21 + t
    int s = row / (B * T21), rem = row % (B * T21);
    int b = rem / T21, t = rem % T21;
    const float* src;
    if (s == 0) src = se;
    else { int tt = t + s - 1; if (tt > 15) tt = 15; src = embed + (size_t)y[b * T2 + tt] * E; }
    sb[j] = src[j];
    __syncthreads();
    float a0 = 0, a1 = 0, a2 = 0, a3 = 0;
    for (int k = 0; k < E; ++k) {
        float x = sb[k];
        const float* w = xT + (size_t)k * G4;
        a0 += x * w[j]; a1 += x * w[256 + j]; a2 += x * w[512 + j]; a3 += x * w[768 + j];
    }
    *(float4*)&pre_xi[(size_t)row * G4 + 4 * j] = make_float4(a0, a1, a2, a3);
}

// ---------------- LSTM bodies (64Mx64N tile, 4 waves n-split, fused nonlinearity) ----------------
// L0 step: reads IN cols 0-255 (h1_prev), writes OUT cols 0-255 (h1_new)
__device__ __forceinline__ void lstm0_body(int step, int l, float* smem,
        const short* __restrict__ IN, const short* __restrict__ whh0i,
        const float* __restrict__ pre_ctxi, const float* __restrict__ pre_xi,
        float* __restrict__ c1, short* __restrict__ OUT) {
    int tid = threadIdx.x;
    int wave = tid >> 6, lane = tid & 63, ln = lane & 15, kg = lane >> 4;
    int mb = l >> 4, nb = l & 15;
    int m0 = mb * 64, n0 = nb * 64;
    const short* Ap = IN + (size_t)(m0 + ln) * 512 + kg * 8;
    const short* Bp = whh0i + (size_t)(n0 + wave * 16 + ln) * 256 + kg * 8;
    f32x4 acc[4] = {};
    gemm_acc<2, 512>(Ap, Bp, acc);
#pragma unroll
    for (int mf = 0; mf < 4; ++mf)
#pragma unroll
        for (int r = 0; r < 4; ++r)
            smem[(mf * 16 + kg * 4 + r) * 68 + wave * 16 + ln] = acc[mf][r];
    __syncthreads();
    int jlo = nb * 16;
#pragma unroll
    for (int q = 0; q < 4; ++q) {
        int item = q * 256 + tid;
        int c = item >> 4, jj = item & 15;
        int cell = m0 + c;
        int j = jlo + jj;
        float4 g = *(float4*)&smem[c * 68 + 4 * jj];
        int bi = cell / T21;
        int bb = bi >> 4;
        int t = cell % T21;
        int prow = (step * B + bb) * T21 + t;
        float4 pc = *(const float4*)&pre_ctxi[(size_t)bi * G4 + 4 * j];
        float4 px = *(const float4*)&pre_xi[(size_t)prow * G4 + 4 * j];
        float ig = g.x + pc.x + px.x, fg = g.y + pc.y + px.y;
        float gg = g.z + pc.z + px.z, og = g.w + pc.w + px.w;
        float cold = c1[(size_t)cell * H + j];
        float cn = sigm(fg) * cold + sigm(ig) * ftanh(gg);
        float hn = sigm(og) * ftanh(cn);
        c1[(size_t)cell * H + j] = cn;
        OUT[(size_t)cell * 512 + j] = f2b(hn);
    }
}

// L1 step: reads IN full 512 cols, writes h2 slab + OUT cols 256-511
__device__ __forceinline__ void lstm1_body(int l, float* smem,
        const short* __restrict__ IN, const short* __restrict__ w1i,
        const float* __restrict__ b1i, float* __restrict__ c2,
        short* __restrict__ slab, short* __restrict__ OUT) {
    int tid = threadIdx.x;
    int wave = tid >> 6, lane = tid & 63, ln = lane & 15, kg = lane >> 4;
    int mb = l >> 4, nb = l & 15;
    int m0 = mb * 64, n0 = nb * 64;
    const short* Ap = IN + (size_t)(m0 + ln) * 512 + kg * 8;
    const short* Bp = w1i + (size_t)(n0 + wave * 16 + ln) * 512 + kg * 8;
    f32x4 acc[4] = {};
    gemm_acc<4, 512>(Ap, Bp, acc);
#pragma unroll
    for (int mf = 0; mf < 4; ++mf)
#pragma unroll
        for (int r = 0; r < 4; ++r)
            smem[(mf * 16 + kg * 4 + r) * 68 + wave * 16 + ln] = acc[mf][r];
    __syncthreads();
    int jlo = nb * 16;
#pragma unroll
    for (int q = 0; q < 4; ++q) {
        int item = q * 256 + tid;
        int c = item >> 4, jj = item & 15;
        int cell = m0 + c;
        int j = jlo + jj;
        float4 g = *(float4*)&smem[c * 68 + 4 * jj];
        float4 bv = *(const float4*)&b1i[4 * j];
        float ig = g.x + bv.x, fg = g.y + bv.y, gg = g.z + bv.z, og = g.w + bv.w;
        float cold = c2[(size_t)cell * H + j];
        float cn = sigm(fg) * cold + sigm(ig) * ftanh(gg);
        float hn = sigm(og) * ftanh(cn);
        c2[(size_t)cell * H + j] = cn;
        short hb = f2b(hn);
        slab[(size_t)cell * 256 + j] = hb;
        OUT[(size_t)cell * 512 + 256 + j] = hb;
    }
}

// merged [L1_s || L0_{s+1}]: bx < n_l1 -> L1_s, else L0_{s+1}
__global__ __launch_bounds__(256, 2) void k_lstm(int s, int n_l1,
        const short* __restrict__ IN, short* __restrict__ OUT, short* __restrict__ slab,
        const short* __restrict__ whh0i, const short* __restrict__ w1i,
        const float* __restrict__ pre_ctxi, const float* __restrict__ pre_xi,
        const float* __restrict__ b1i, float* __restrict__ c1, float* __restrict__ c2) {
    __shared__ float smem[64 * 68];
    int bx = blockIdx.x;
    if (bx < n_l1) lstm1_body(bx, smem, IN, w1i, b1i, c2, slab, OUT);
    else lstm0_body(s + 1, bx - n_l1, smem, IN, whh0i, pre_ctxi, pre_xi, c1, OUT);
}

// ---------------- fc mega-dispatch: all 5 steps, XCD-chunked nb-major tiles ----------------
__global__ __launch_bounds__(256, 2) void k_fc(const short* __restrict__ h2base, const short* __restrict__ Wv,
        const float* __restrict__ fcb, float* __restrict__ psum) {
    __shared__ float smem[256];
    int bx = blockIdx.x;
    // bijective chunked XCD map (N=10625, q=1328, r=1)
    int xcd = bx & 7, idx = bx >> 3;
    int q = NFCT >> 3, r = NFCT & 7;
    int l = xcd * q + (xcd < r ? xcd : r) + idx;
    int nb = l / 85, rem = l % 85;
    int s = rem / 17, mb = rem % 17;
    int m0 = s * NCELL + mb * 64;
    int n0 = nb * 64;
    int tid = threadIdx.x;
    int wave = tid >> 6, lane = tid & 63, ln = lane & 15, kg = lane >> 4;
    const short* Ap = h2base + (size_t)(m0 + ln) * 256 + kg * 8;
    const short* Bp = Wv + (size_t)(n0 + wave * 16 + ln) * 256 + kg * 8;
    f32x4 acc[4] = {};
    gemm_acc<2, 256>(Ap, Bp, acc);
    float fbn = fcb[n0 + wave * 16 + ln];
    float sums[4][4];
#pragma unroll
    for (int mf = 0; mf < 4; ++mf)
#pragma unroll
        for (int rr = 0; rr < 4; ++rr)
            sums[mf][rr] = __expf(acc[mf][rr] + fbn);
#pragma unroll
    for (int mask = 1; mask < 16; mask <<= 1)
#pragma unroll
        for (int mf = 0; mf < 4; ++mf)
#pragma unroll
            for (int rr = 0; rr < 4; ++rr)
                sums[mf][rr] += __shfl_xor(sums[mf][rr], mask);
    if (ln == 0) {
#pragma unroll
        for (int mf = 0; mf < 4; ++mf)
#pragma unroll
            for (int rr = 0; rr < 4; ++rr)
                smem[wave * 64 + mf * 16 + kg * 4 + rr] = sums[mf][rr];
    }
    __syncthreads();
    if (tid < 64) {
        float v = smem[tid] + smem[64 + tid] + smem[128 + tid] + smem[192 + tid];
        psum[(size_t)nb * MROWS + m0 + tid] = v;
    }
}

// ---------------- combine: tgt/EOS dots + sum of 125 psum partials ----------------
__global__ void k_combine(const short* __restrict__ h2all, const short* __restrict__ Wv,
        const float* __restrict__ fcb, const int* __restrict__ y,
        const float* __restrict__ psum, float* __restrict__ sel, float* __restrict__ eosp) {
    int cb = blockIdx.x;                 // s*17 + blk
    int s = cb / 17, blk = cb % 17;
    int tid = threadIdx.x;
    int cl = tid >> 2, q = tid & 3;
    int cell = blk * 64 + cl;
    int b = cell / (T1 * T21);
    int t = cell % T21;
    int tv = 0;
    if (s < SEG) { int tt = t + s; if (tt > 15) tt = 15; tv = y[b * T2 + tt]; }
    const short* hp = h2all + (size_t)(s + 1) * NCELL * 256 + (size_t)cell * 256 + q * 64;
    const short* w1 = Wv + (size_t)tv * 256 + q * 64;
    const short* w2 = Wv + (size_t)EOS * 256 + q * 64;
    float d1 = 0.f, d2 = 0.f;
#pragma unroll
    for (int u = 0; u < 8; ++u) {
        bf16x8 av  = *(const bf16x8*)(hp + u * 8);
        bf16x8 wv1 = *(const bf16x8*)(w1 + u * 8);
        bf16x8 wv2 = *(const bf16x8*)(w2 + u * 8);
#pragma unroll
        for (int e = 0; e < 8; ++e) {
            float a = b2f(av[e]);
            d1 += a * b2f(wv1[e]);
            d2 += a * b2f(wv2[e]);
        }
    }
    d1 += __shfl_xor(d1, 1); d1 += __shfl_xor(d1, 2);
    d2 += __shfl_xor(d2, 1); d2 += __shfl_xor(d2, 2);
    int col = s * NCELL + cell;
    float ss = 0.f;
    for (int v2 = q * 32; v2 < q * 32 + 32 && v2 < 125; ++v2)
        ss += psum[(size_t)v2 * MROWS + col];
    ss += __shfl_xor(ss, 1); ss += __shfl_xor(ss, 2);
    if (q == 0) {
        float lse = __logf(ss);
        sel[s * NCELL + cell]  = d1 + fcb[tv]  - lse;
        eosp[s * NCELL + cell] = d2 + fcb[EOS] - lse;
    }
}

// ---------------- final DP, fully LDS-resident ----------------
__global__ void k_dp(const float* __restrict__ sel, const float* __restrict__ eosp, float* __restrict__ out) {
    __shared__ float row[SEG + 1][NCELL];
    __shared__ float alpha[B][T21];
    int tid = threadIdx.x;
    for (int c = tid; c < NCELL; c += 256) {
        float cum = 0.f;
        row[0][c] = eosp[c];
#pragma unroll
        for (int j = 1; j <= SEG; ++j) {
            cum += sel[(j - 1) * NCELL + c];
            row[j][c] = cum + eosp[j * NCELL + c];
        }
    }
    int b = tid / T21, t = tid % T21;
    bool act = tid < B * T21;
    if (act) alpha[b][t] = (t == 0) ? 0.f : NEGV;
    __syncthreads();
    for (int i = 0; i < T1; ++i) {
        float val = NEGV;
        if (act) {
            float terms[SEG + 1];
            float mx = -3.4e38f;
            int cnt2 = 0;
            for (int j = 0; j <= SEG && j <= t; ++j) {
                int cell = (b * T1 + i) * T21 + (t - j);
                float term = alpha[b][t - j] + row[j][cell];
                terms[cnt2++] = term;
                mx = fmaxf(mx, term);
            }
            float ssum = 0.f;
            for (int k2 = 0; k2 < cnt2; ++k2) ssum += __expf(terms[k2] - mx);
            val = mx + __logf(ssum);
        }
        __syncthreads();
        if (act) alpha[b][t] = val;
        __syncthreads();
    }
    if (act && t == T2) out[b] = alpha[b][T2];
}

extern "C" void kernel_launch(void* const* d_in, const int* in_sizes, int n_in,
                              void* d_out, int out_size, void* d_ws, size_t ws_size,
                              hipStream_t stream) {
    const int*   y     = (const int*)d_in[0];
    const float* enc   = (const float*)d_in[1];
    const float* embed = (const float*)d_in[2];
    const float* se    = (const float*)d_in[3];
    const float* phw   = (const float*)d_in[4];
    const float* phb   = (const float*)d_in[5];
    const float* pcw   = (const float*)d_in[6];
    const float* pcb   = (const float*)d_in[7];
    const float* wih0  = (const float*)d_in[8];
    const float* whh0  = (const float*)d_in[9];
    const float* b0    = (const float*)d_in[10];
    const float* wih1  = (const float*)d_in[11];
    const float* whh1  = (const float*)d_in[12];
    const float* b1    = (const float*)d_in[13];
    const float* fcw   = (const float*)d_in[14];
    const float* fcb   = (const float*)d_in[15];

    float* ws = (float*)d_ws;
    size_t off = 0;
    auto alloc = [&](size_t n) { float* p = ws + off; off += n; return p; };
    float* projhT   = alloc((size_t)ENC * H);
    float* projcT   = alloc((size_t)ENC * H);
    float* ctxT     = alloc((size_t)H * G4);
    float* xT       = alloc((size_t)E * G4);
    float* h0       = alloc((size_t)B * T1 * H);
    float* c0       = alloc((size_t)B * T1 * H);
    float* pre_ctxi = alloc((size_t)B * T1 * G4);
    float* pre_xi   = alloc((size_t)(SEG + 1) * B * T21 * G4);
    float* c1       = alloc((size_t)NCELL * H);
    float* c2       = alloc((size_t)NCELL * H);
    float* b1i      = alloc((size_t)G4);
    float* selbuf   = alloc((size_t)(SEG + 1) * NCELL);
    float* eospbuf  = alloc((size_t)(SEG + 1) * NCELL);
    float* psum     = alloc((size_t)125 * MROWS);
    short* hc0      = (short*)alloc((size_t)NCELL * 512 / 2);
    short* hc1      = (short*)alloc((size_t)NCELL * 512 / 2);
    short* h2all    = (short*)alloc((size_t)6 * NCELL * 256 / 2);
    short* whh0i    = (short*)alloc((size_t)G4 * 256 / 2);
    short* w1i      = (short*)alloc((size_t)G4 * 512 / 2);
    short* fcwbf    = (short*)alloc((size_t)V * H / 2);

    hipLaunchKernelGGL(k_setup, dim3(14148), dim3(256), 0, stream,
                       fcw, whh0, wih1, whh1, phw, pcw, wih0, b1,
                       fcwbf, whh0i, w1i, projhT, projcT, ctxT, xT, b1i);
    hipLaunchKernelGGL(k_init_state, dim3(B * T1), dim3(256), 0, stream,
                       enc, projhT, phb, projcT, pcb, h0, c0);
    hipLaunchKernelGGL(k_init2, dim3(NCELL + 64 + (SEG + 1) * B * T21), dim3(256), 0, stream,
                       y, embed, se, h0, c0, ctxT, xT, b0, c1, c2, hc0, hc1,
                       pre_ctxi, pre_xi);

    // H_{-1}=hc0, H_0=hc1, H_1=hc0, ... (H_s = hcb[(s+1)&1])
    short* hcb[2] = { hc0, hc1 };
    // D: L0_0 only (s=-1, n_l1=0): IN=H_{-1}=hc0, OUT=H_0=hc1
    hipLaunchKernelGGL(k_lstm, dim3(NL), dim3(256), 0, stream,
                       -1, 0, hcb[0], hcb[1], h2all,
                       whh0i, w1i, pre_ctxi, pre_xi, b1i, c1, c2);
    for (int s = 0; s < SEG; ++s) {
        // [L1_s || L0_{s+1}]: IN=H_s, OUT=H_{s+1}, slab=h2all[s+1]
        hipLaunchKernelGGL(k_lstm, dim3(2 * NL), dim3(256), 0, stream,
                           s, NL, hcb[(s + 1) & 1], hcb[s & 1],
                           h2all + (size_t)(s + 1) * NCELL * 256,
                           whh0i, w1i, pre_ctxi, pre_xi, b1i, c1, c2);
    }
    // L1_4 only: IN=H_4=hc1, OUT=hc0 (dummy upper-half writes), slab=h2all[5]
    hipLaunchKernelGGL(k_lstm, dim3(NL), dim3(256), 0, stream,
                       4, NL, hcb[1], hcb[0],
                       h2all + (size_t)5 * NCELL * 256,
                       whh0i, w1i, pre_ctxi, pre_xi, b1i, c1, c2);

    hipLaunchKernelGGL(k_fc, dim3(NFCT), dim3(256), 0, stream,
                       h2all + (size_t)NCELL * 256, fcwbf, fcb, psum);
    hipLaunchKernelGGL(k_combine, dim3(85), dim3(256), 0, stream,
                       h2all, fcwbf, fcb, y, psum, selbuf, eospbuf);
    hipLaunchKernelGGL(k_dp, dim3(1), dim3(256), 0, stream, selbuf, eospbuf, (float*)d_out);
}

// Round 9
// 201.357 us; speedup vs baseline: 2.2890x; 2.0775x over previous
//
#include <hip/hip_runtime.h>
#include <math.h>

#define B 4
#define T1 16
#define T2 16
#define SEG 4
#define V 8000
#define E 256
#define H 256
#define ENC 512
#define EOS 2
#define NEGV -1e30f
#define G4 1024
#define NCELL 1088
#define T21 17
#define NL 272        // 17*16 lstm tiles per layer-step
#define MROWS 5440    // 5*1088 batched fc rows
#define NFCT 10625    // 5*17*125 fc tiles

typedef __attribute__((ext_vector_type(4))) float f32x4;
typedef __attribute__((ext_vector_type(8))) short bf16x8;

__device__ __forceinline__ float sigm(float x) { return 1.f / (1.f + __expf(-x)); }
__device__ __forceinline__ float ftanh(float x) { float e = __expf(2.f * x); return 1.f - 2.f / (e + 1.f); }
__device__ __forceinline__ float b2f(short x) {
    unsigned u = ((unsigned)(unsigned short)x) << 16;
    return __builtin_bit_cast(float, u);
}
__device__ __forceinline__ short f2b(float f) {
    unsigned u = __builtin_bit_cast(unsigned, f);
    unsigned r = (u + 0x7fffu + ((u >> 16) & 1u)) >> 16;
    return (short)r;
}

// ---- async stage of a 64-row x 512-byte tile into LDS (linear dest, inverse-swizzled src) ----
// LDS[row][c16] = G[row][c16 ^ (row&7)]  (16B granules). 8 issues x 256 lanes x 16B = 32 KB.
__device__ __forceinline__ void stage64(const char* g0, size_t gstrideB, int kOffB, char* lds) {
    int tid = threadIdx.x;
#pragma unroll
    for (int it = 0; it < 8; ++it) {
        int chunk = it * 256 + tid;          // 0..2047
        int row = chunk >> 5;
        int c16 = chunk & 31;
        const char* src = g0 + (size_t)row * gstrideB + kOffB + ((c16 ^ (row & 7)) << 4);
        __builtin_amdgcn_global_load_lds((const __attribute__((address_space(1))) void*)src,
                                         (__attribute__((address_space(3))) void*)(lds + chunk * 16),
                                         16, 0, 0);
    }
}

// swizzled fragment read: logical (row, col16) -> ds_read_b128
__device__ __forceinline__ bf16x8 lds_frag(const char* lds, int row, int col16) {
    return *(const bf16x8*)(lds + row * 512 + ((col16 ^ (row & 7)) << 4));
}

// per-wave 16Mx64N x K=256 from staged tiles: 8 a-reads + 32 b-reads + 32 MFMA
__device__ __forceinline__ void mma_tile(const char* smA, const char* smB,
                                         int wave, int ln, int kg, f32x4 acc[4]) {
#pragma unroll
    for (int ks = 0; ks < 8; ++ks) {
        bf16x8 a = lds_frag(smA, wave * 16 + ln, ks * 4 + kg);
#pragma unroll
        for (int nf = 0; nf < 4; ++nf) {
            bf16x8 b = lds_frag(smB, nf * 16 + ln, ks * 4 + kg);
            acc[nf] = __builtin_amdgcn_mfma_f32_16x16x32_bf16(a, b, acc[nf], 0, 0, 0);
        }
    }
}

// ---------------- fused setup ----------------
__global__ void k_setup(const float* __restrict__ fcw, const float* __restrict__ whh0,
                        const float* __restrict__ wih1, const float* __restrict__ whh1,
                        const float* __restrict__ phw, const float* __restrict__ pcw,
                        const float* __restrict__ wih0, const float* __restrict__ b1,
                        short* __restrict__ fcwbf, short* __restrict__ whh0i, short* __restrict__ w1i,
                        float* __restrict__ projhT, float* __restrict__ projcT,
                        float* __restrict__ ctxT, float* __restrict__ xT, float* __restrict__ b1i) {
    int bid = blockIdx.x, tid = threadIdx.x;
    if (bid < 8000) { int i = bid * 256 + tid; fcwbf[i] = f2b(fcw[i]); return; }
    bid -= 8000;
    if (bid < 1024) {
        int i = bid * 256 + tid; int gp = i >> 8, k = i & 255; int j = gp >> 2, gate = gp & 3;
        whh0i[i] = f2b(whh0[(size_t)(gate * 256 + j) * 256 + k]); return;
    }
    bid -= 1024;
    if (bid < 2048) {
        int i = bid * 256 + tid; int gp = i >> 9, k = i & 511; int j = gp >> 2, gate = gp & 3;
        float v = (k < 256) ? wih1[(size_t)(gate * 256 + j) * 256 + k]
                            : whh1[(size_t)(gate * 256 + j) * 256 + (k - 256)];
        w1i[i] = f2b(v); return;
    }
    bid -= 2048;
    if (bid < 512) { int i = bid * 256 + tid; int k = i >> 8, r = i & 255; projhT[i] = phw[(size_t)r * ENC + k]; return; }
    bid -= 512;
    if (bid < 512) { int i = bid * 256 + tid; int k = i >> 8, r = i & 255; projcT[i] = pcw[(size_t)r * ENC + k]; return; }
    bid -= 512;
    if (bid < 2048) {
        int i = bid * 256 + tid; int g = i >> 9, k = i & 511; float v = wih0[i];
        if (k < 256) ctxT[(size_t)k * G4 + g] = v; else xT[(size_t)(k - 256) * G4 + g] = v;
        return;
    }
    bid -= 2048;
    if (bid < 4) { int i = bid * 256 + tid; int j = i >> 2, gate = i & 3; b1i[i] = b1[gate * 256 + j]; return; }
}

// ---------------- h0/c0 ----------------
__global__ void k_init_state(const float* __restrict__ enc, const float* __restrict__ phT,
                             const float* __restrict__ phb, const float* __restrict__ pcT,
                             const float* __restrict__ pcb, float* __restrict__ h0, float* __restrict__ c0) {
    __shared__ float eo[ENC];
    int bi = blockIdx.x;
    int b = bi / T1, i = bi % T1;
    int j = threadIdx.x;
    for (int e = j; e < ENC; e += 256) eo[e] = enc[(size_t)(i * B + b) * ENC + e];
    __syncthreads();
    float ha = phb[j], ca = pcb[j];
    for (int e = 0; e < ENC; ++e) {
        float x = eo[e];
        ha += x * phT[(size_t)e * H + j];
        ca += x * pcT[(size_t)e * H + j];
    }
    h0[(size_t)bi * H + j] = ha;
    c0[(size_t)bi * H + j] = ca;
}

// ---------------- fused init ----------------
__global__ void k_init2(const int* __restrict__ y, const float* __restrict__ embed, const float* __restrict__ se,
                        const float* __restrict__ h0, const float* __restrict__ c0,
                        const float* __restrict__ ctxT, const float* __restrict__ xT,
                        const float* __restrict__ b0,
                        float* __restrict__ c1, float* __restrict__ c2,
                        short* __restrict__ hcA, short* __restrict__ hcB,
                        float* __restrict__ pre_ctxi, float* __restrict__ pre_xi) {
    __shared__ float sb[256];
    int bid = blockIdx.x, j = threadIdx.x;
    if (bid < NCELL) {
        int cell = bid, bi = cell / T21;
        c1[(size_t)cell * H + j] = c0[(size_t)bi * H + j];
        c2[(size_t)cell * H + j] = 0.f;
        hcA[(size_t)cell * 512 + j] = f2b(h0[(size_t)bi * H + j]);  // h1_{-1}
        hcB[(size_t)cell * 512 + 256 + j] = 0;                      // h2_{-1}
        return;
    }
    bid -= NCELL;
    if (bid < 64) {
        int bi = bid;
        sb[j] = h0[(size_t)bi * H + j];
        __syncthreads();
        float a0 = b0[j], a1 = b0[256 + j], a2 = b0[512 + j], a3 = b0[768 + j];
        for (int k = 0; k < H; ++k) {
            float x = sb[k];
            const float* w = ctxT + (size_t)k * G4;
            a0 += x * w[j]; a1 += x * w[256 + j]; a2 += x * w[512 + j]; a3 += x * w[768 + j];
        }
        *(float4*)&pre_ctxi[(size_t)bi * G4 + 4 * j] = make_float4(a0, a1, a2, a3);
        return;
    }
    bid -= 64;
    int row = bid;                    // (s*B + b)*T21 + t
    int s = row / (B * T21), rem = row % (B * T21);
    int b = rem / T21, t = rem % T21;
    const float* src;
    if (s == 0) src = se;
    else { int tt = t + s - 1; if (tt > 15) tt = 15; src = embed + (size_t)y[b * T2 + tt] * E; }
    sb[j] = src[j];
    __syncthreads();
    float a0 = 0, a1 = 0, a2 = 0, a3 = 0;
    for (int k = 0; k < E; ++k) {
        float x = sb[k];
        const float* w = xT + (size_t)k * G4;
        a0 += x * w[j]; a1 += x * w[256 + j]; a2 += x * w[512 + j]; a3 += x * w[768 + j];
    }
    *(float4*)&pre_xi[(size_t)row * G4 + 4 * j] = make_float4(a0, a1, a2, a3);
}

// ---------------- LSTM bodies: LDS-staged 64Mx64N tile ----------------
__device__ __forceinline__ void lstm0_body(int step, int l, char* smA, char* smB,
        const short* __restrict__ IN, const short* __restrict__ whh0i,
        const float* __restrict__ pre_ctxi, const float* __restrict__ pre_xi,
        float* __restrict__ c1, short* __restrict__ OUT) {
    int tid = threadIdx.x;
    int wave = tid >> 6, lane = tid & 63, ln = lane & 15, kg = lane >> 4;
    int mb = l >> 4, nb = l & 15;
    int m0 = mb * 64, n0 = nb * 64;
    stage64((const char*)(IN + (size_t)m0 * 512), 1024, 0, smA);      // h1_prev cols 0-255
    stage64((const char*)(whh0i + (size_t)n0 * 256), 512, 0, smB);
    __syncthreads();
    f32x4 acc[4] = {};
    mma_tile(smA, smB, wave, ln, kg, acc);
    __syncthreads();
    float* sg = (float*)smA;
#pragma unroll
    for (int nf = 0; nf < 4; ++nf)
#pragma unroll
        for (int r = 0; r < 4; ++r)
            sg[(wave * 16 + kg * 4 + r) * 68 + nf * 16 + ln] = acc[nf][r];
    __syncthreads();
    int jlo = nb * 16;
#pragma unroll
    for (int q2 = 0; q2 < 4; ++q2) {
        int item = q2 * 256 + tid;
        int c = item >> 4, jj = item & 15;
        int cell = m0 + c;
        int j = jlo + jj;
        float4 g = *(float4*)&sg[c * 68 + 4 * jj];
        int bi = cell / T21;
        int bb = bi >> 4;
        int t = cell % T21;
        int prow = (step * B + bb) * T21 + t;
        float4 pc = *(const float4*)&pre_ctxi[(size_t)bi * G4 + 4 * j];
        float4 px = *(const float4*)&pre_xi[(size_t)prow * G4 + 4 * j];
        float ig = g.x + pc.x + px.x, fg = g.y + pc.y + px.y;
        float gg = g.z + pc.z + px.z, og = g.w + pc.w + px.w;
        float cold = c1[(size_t)cell * H + j];
        float cn = sigm(fg) * cold + sigm(ig) * ftanh(gg);
        float hn = sigm(og) * ftanh(cn);
        c1[(size_t)cell * H + j] = cn;
        OUT[(size_t)cell * 512 + j] = f2b(hn);
    }
}

__device__ __forceinline__ void lstm1_body(int l, char* smA, char* smB,
        const short* __restrict__ IN, const short* __restrict__ w1i,
        const float* __restrict__ b1i, float* __restrict__ c2,
        short* __restrict__ slab, short* __restrict__ OUT) {
    int tid = threadIdx.x;
    int wave = tid >> 6, lane = tid & 63, ln = lane & 15, kg = lane >> 4;
    int mb = l >> 4, nb = l & 15;
    int m0 = mb * 64, n0 = nb * 64;
    f32x4 acc[4] = {};
#pragma unroll
    for (int kh = 0; kh < 2; ++kh) {
        if (kh) __syncthreads();
        stage64((const char*)(IN + (size_t)m0 * 512), 1024, kh * 512, smA);
        stage64((const char*)(w1i + (size_t)n0 * 512), 1024, kh * 512, smB);
        __syncthreads();
        mma_tile(smA, smB, wave, ln, kg, acc);
    }
    __syncthreads();
    float* sg = (float*)smA;
#pragma unroll
    for (int nf = 0; nf < 4; ++nf)
#pragma unroll
        for (int r = 0; r < 4; ++r)
            sg[(wave * 16 + kg * 4 + r) * 68 + nf * 16 + ln] = acc[nf][r];
    __syncthreads();
    int jlo = nb * 16;
#pragma unroll
    for (int q2 = 0; q2 < 4; ++q2) {
        int item = q2 * 256 + tid;
        int c = item >> 4, jj = item & 15;
        int cell = m0 + c;
        int j = jlo + jj;
        float4 g = *(float4*)&sg[c * 68 + 4 * jj];
        float4 bv = *(const float4*)&b1i[4 * j];
        float ig = g.x + bv.x, fg = g.y + bv.y, gg = g.z + bv.z, og = g.w + bv.w;
        float cold = c2[(size_t)cell * H + j];
        float cn = sigm(fg) * cold + sigm(ig) * ftanh(gg);
        float hn = sigm(og) * ftanh(cn);
        c2[(size_t)cell * H + j] = cn;
        short hb = f2b(hn);
        slab[(size_t)cell * 256 + j] = hb;
        OUT[(size_t)cell * 512 + 256 + j] = hb;
    }
}

// merged [L1_s || L0_{s+1}]
__global__ __launch_bounds__(256, 2) void k_lstm(int s, int n_l1,
        const short* __restrict__ IN, short* __restrict__ OUT, short* __restrict__ slab,
        const short* __restrict__ whh0i, const short* __restrict__ w1i,
        const float* __restrict__ pre_ctxi, const float* __restrict__ pre_xi,
        const float* __restrict__ b1i, float* __restrict__ c1, float* __restrict__ c2) {
    __shared__ char smem[65536];
    char* smA = smem;
    char* smB = smem + 32768;
    int bx = blockIdx.x;
    if (bx < n_l1) lstm1_body(bx, smA, smB, IN, w1i, b1i, c2, slab, OUT);
    else lstm0_body(s + 1, bx - n_l1, smA, smB, IN, whh0i, pre_ctxi, pre_xi, c1, OUT);
}

// ---------------- fc mega-dispatch: LDS-staged, XCD-chunked nb-major ----------------
__global__ __launch_bounds__(256, 2) void k_fc(const short* __restrict__ h2base, const short* __restrict__ Wv,
        const float* __restrict__ fcb, float* __restrict__ psum) {
    __shared__ char smem[65536];
    char* smA = smem;
    char* smB = smem + 32768;
    int bx = blockIdx.x;
    int xcd = bx & 7, idx = bx >> 3;
    int q = NFCT >> 3, r = NFCT & 7;
    int l = xcd * q + (xcd < r ? xcd : r) + idx;
    int nb = l / 85, rem = l % 85;
    int s = rem / 17, mb = rem % 17;
    int m0 = s * NCELL + mb * 64;
    int n0 = nb * 64;
    int tid = threadIdx.x;
    int wave = tid >> 6, lane = tid & 63, ln = lane & 15, kg = lane >> 4;
    stage64((const char*)(h2base + (size_t)m0 * 256), 512, 0, smA);
    stage64((const char*)(Wv + (size_t)n0 * 256), 512, 0, smB);
    __syncthreads();
    f32x4 acc[4] = {};
    mma_tile(smA, smB, wave, ln, kg, acc);
    // epilogue: each wave owns complete 64-col rows -> direct psum store
    float rs[4] = {0.f, 0.f, 0.f, 0.f};
#pragma unroll
    for (int nf = 0; nf < 4; ++nf) {
        float fbn = fcb[n0 + nf * 16 + ln];
#pragma unroll
        for (int r2 = 0; r2 < 4; ++r2)
            rs[r2] += __expf(acc[nf][r2] + fbn);
    }
#pragma unroll
    for (int mask = 1; mask < 16; mask <<= 1)
#pragma unroll
        for (int r2 = 0; r2 < 4; ++r2)
            rs[r2] += __shfl_xor(rs[r2], mask);
    if (ln == 0) {
#pragma unroll
        for (int r2 = 0; r2 < 4; ++r2)
            psum[(size_t)nb * MROWS + m0 + wave * 16 + kg * 4 + r2] = rs[r2];
    }
}

// ---------------- combine: tgt/EOS dots + sum of 125 psum partials ----------------
__global__ void k_combine(const short* __restrict__ h2all, const short* __restrict__ Wv,
        const float* __restrict__ fcb, const int* __restrict__ y,
        const float* __restrict__ psum, float* __restrict__ sel, float* __restrict__ eosp) {
    int cb = blockIdx.x;                 // s*17 + blk
    int s = cb / 17, blk = cb % 17;
    int tid = threadIdx.x;
    int cl = tid >> 2, q = tid & 3;
    int cell = blk * 64 + cl;
    int b = cell / (T1 * T21);
    int t = cell % T21;
    int tv = 0;
    if (s < SEG) { int tt = t + s; if (tt > 15) tt = 15; tv = y[b * T2 + tt]; }
    const short* hp = h2all + (size_t)(s + 1) * NCELL * 256 + (size_t)cell * 256 + q * 64;
    const short* w1 = Wv + (size_t)tv * 256 + q * 64;
    const short* w2 = Wv + (size_t)EOS * 256 + q * 64;
    float d1 = 0.f, d2 = 0.f;
#pragma unroll
    for (int u = 0; u < 8; ++u) {
        bf16x8 av  = *(const bf16x8*)(hp + u * 8);
        bf16x8 wv1 = *(const bf16x8*)(w1 + u * 8);
        bf16x8 wv2 = *(const bf16x8*)(w2 + u * 8);
#pragma unroll
        for (int e = 0; e < 8; ++e) {
            float a = b2f(av[e]);
            d1 += a * b2f(wv1[e]);
            d2 += a * b2f(wv2[e]);
        }
    }
    d1 += __shfl_xor(d1, 1); d1 += __shfl_xor(d1, 2);
    d2 += __shfl_xor(d2, 1); d2 += __shfl_xor(d2, 2);
    int col = s * NCELL + cell;
    float ss = 0.f;
    for (int v2 = q * 32; v2 < q * 32 + 32 && v2 < 125; ++v2)
        ss += psum[(size_t)v2 * MROWS + col];
    ss += __shfl_xor(ss, 1); ss += __shfl_xor(ss, 2);
    if (q == 0) {
        float lse = __logf(ss);
        sel[s * NCELL + cell]  = d1 + fcb[tv]  - lse;
        eosp[s * NCELL + cell] = d2 + fcb[EOS] - lse;
    }
}

// ---------------- final DP, fully LDS-resident ----------------
__global__ void k_dp(const float* __restrict__ sel, const float* __restrict__ eosp, float* __restrict__ out) {
    __shared__ float row[SEG + 1][NCELL];
    __shared__ float alpha[B][T21];
    int tid = threadIdx.x;
    for (int c = tid; c < NCELL; c += 256) {
        float cum = 0.f;
        row[0][c] = eosp[c];
#pragma unroll
        for (int j = 1; j <= SEG; ++j) {
            cum += sel[(j - 1) * NCELL + c];
            row[j][c] = cum + eosp[j * NCELL + c];
        }
    }
    int b = tid / T21, t = tid % T21;
    bool act = tid < B * T21;
    if (act) alpha[b][t] = (t == 0) ? 0.f : NEGV;
    __syncthreads();
    for (int i = 0; i < T1; ++i) {
        float val = NEGV;
        if (act) {
            float terms[SEG + 1];
            float mx = -3.4e38f;
            int cnt2 = 0;
            for (int j = 0; j <= SEG && j <= t; ++j) {
                int cell = (b * T1 + i) * T21 + (t - j);
                float term = alpha[b][t - j] + row[j][cell];
                terms[cnt2++] = term;
                mx = fmaxf(mx, term);
            }
            float ssum = 0.f;
            for (int k2 = 0; k2 < cnt2; ++k2) ssum += __expf(terms[k2] - mx);
            val = mx + __logf(ssum);
        }
        __syncthreads();
        if (act) alpha[b][t] = val;
        __syncthreads();
    }
    if (act && t == T2) out[b] = alpha[b][T2];
}

extern "C" void kernel_launch(void* const* d_in, const int* in_sizes, int n_in,
                              void* d_out, int out_size, void* d_ws, size_t ws_size,
                              hipStream_t stream) {
    const int*   y     = (const int*)d_in[0];
    const float* enc   = (const float*)d_in[1];
    const float* embed = (const float*)d_in[2];
    const float* se    = (const float*)d_in[3];
    const float* phw   = (const float*)d_in[4];
    const float* phb   = (const float*)d_in[5];
    const float* pcw   = (const float*)d_in[6];
    const float* pcb   = (const float*)d_in[7];
    const float* wih0  = (const float*)d_in[8];
    const float* whh0  = (const float*)d_in[9];
    const float* b0    = (const float*)d_in[10];
    const float* wih1  = (const float*)d_in[11];
    const float* whh1  = (const float*)d_in[12];
    const float* b1    = (const float*)d_in[13];
    const float* fcw   = (const float*)d_in[14];
    const float* fcb   = (const float*)d_in[15];

    float* ws = (float*)d_ws;
    size_t off = 0;
    auto alloc = [&](size_t n) { float* p = ws + off; off += n; return p; };
    float* projhT   = alloc((size_t)ENC * H);
    float* projcT   = alloc((size_t)ENC * H);
    float* ctxT     = alloc((size_t)H * G4);
    float* xT       = alloc((size_t)E * G4);
    float* h0       = alloc((size_t)B * T1 * H);
    float* c0       = alloc((size_t)B * T1 * H);
    float* pre_ctxi = alloc((size_t)B * T1 * G4);
    float* pre_xi   = alloc((size_t)(SEG + 1) * B * T21 * G4);
    float* c1       = alloc((size_t)NCELL * H);
    float* c2       = alloc((size_t)NCELL * H);
    float* b1i      = alloc((size_t)G4);
    float* selbuf   = alloc((size_t)(SEG + 1) * NCELL);
    float* eospbuf  = alloc((size_t)(SEG + 1) * NCELL);
    float* psum     = alloc((size_t)125 * MROWS);
    short* hc0      = (short*)alloc((size_t)NCELL * 512 / 2);
    short* hc1      = (short*)alloc((size_t)NCELL * 512 / 2);
    short* h2all    = (short*)alloc((size_t)6 * NCELL * 256 / 2);
    short* whh0i    = (short*)alloc((size_t)G4 * 256 / 2);
    short* w1i      = (short*)alloc((size_t)G4 * 512 / 2);
    short* fcwbf    = (short*)alloc((size_t)V * H / 2);

    hipLaunchKernelGGL(k_setup, dim3(14148), dim3(256), 0, stream,
                       fcw, whh0, wih1, whh1, phw, pcw, wih0, b1,
                       fcwbf, whh0i, w1i, projhT, projcT, ctxT, xT, b1i);
    hipLaunchKernelGGL(k_init_state, dim3(B * T1), dim3(256), 0, stream,
                       enc, projhT, phb, projcT, pcb, h0, c0);
    hipLaunchKernelGGL(k_init2, dim3(NCELL + 64 + (SEG + 1) * B * T21), dim3(256), 0, stream,
                       y, embed, se, h0, c0, ctxT, xT, b0, c1, c2, hc0, hc1,
                       pre_ctxi, pre_xi);

    // H_{-1}=hc0, H_0=hc1, H_1=hc0, ... (H_s = hcb[(s+1)&1])
    short* hcb[2] = { hc0, hc1 };
    // L0_0 only: IN=H_{-1}=hc0, OUT=H_0=hc1
    hipLaunchKernelGGL(k_lstm, dim3(NL), dim3(256), 0, stream,
                       -1, 0, hcb[0], hcb[1], h2all,
                       whh0i, w1i, pre_ctxi, pre_xi, b1i, c1, c2);
    for (int s = 0; s < SEG; ++s) {
        // [L1_s || L0_{s+1}]: IN=H_s, OUT=H_{s+1}, slab=h2all[s+1]
        hipLaunchKernelGGL(k_lstm, dim3(2 * NL), dim3(256), 0, stream,
                           s, NL, hcb[(s + 1) & 1], hcb[s & 1],
                           h2all + (size_t)(s + 1) * NCELL * 256,
                           whh0i, w1i, pre_ctxi, pre_xi, b1i, c1, c2);
    }
    // L1_4 only: IN=H_4=hc1, OUT=hc0 (dummy upper writes), slab=h2all[5]
    hipLaunchKernelGGL(k_lstm, dim3(NL), dim3(256), 0, stream,
                       4, NL, hcb[1], hcb[0],
                       h2all + (size_t)5 * NCELL * 256,
                       whh0i, w1i, pre_ctxi, pre_xi, b1i, c1, c2);

    hipLaunchKernelGGL(k_fc, dim3(NFCT), dim3(256), 0, stream,
                       h2all + (size_t)NCELL * 256, fcwbf, fcb, psum);
    hipLaunchKernelGGL(k_combine, dim3(85), dim3(256), 0, stream,
                       h2all, fcwbf, fcb, y, psum, selbuf, eospbuf);
    hipLaunchKernelGGL(k_dp, dim3(1), dim3(256), 0, stream, selbuf, eospbuf, (float*)d_out);
}

// Round 10
// 186.629 us; speedup vs baseline: 2.4696x; 1.0789x over previous
//
#include <hip/hip_runtime.h>
#include <math.h>

#define B 4
#define T1 16
#define T2 16
#define SEG 4
#define V 8000
#define E 256
#define H 256
#define ENC 512
#define EOS 2
#define NEGV -1e30f
#define G4 1024
#define NCELL 1088
#define T21 17
#define NL 272        // 17*16 lstm tiles per layer-step
#define MP 5504       // padded batched fc rows (43*128)
#define NTM 43        // fc m-tiles (128 rows)
#define NTN 63        // fc n-tiles (128 cols, last half)
#define NFCT (NTM*NTN) // 2709 fc tiles
#define NPART 126     // psum partials (63 nb * 2 wn)

typedef __attribute__((ext_vector_type(4))) float f32x4;
typedef __attribute__((ext_vector_type(8))) short bf16x8;

__device__ __forceinline__ float sigm(float x) { return 1.f / (1.f + __expf(-x)); }
__device__ __forceinline__ float ftanh(float x) { float e = __expf(2.f * x); return 1.f - 2.f / (e + 1.f); }
__device__ __forceinline__ float b2f(short x) {
    unsigned u = ((unsigned)(unsigned short)x) << 16;
    return __builtin_bit_cast(float, u);
}
__device__ __forceinline__ short f2b(float f) {
    unsigned u = __builtin_bit_cast(unsigned, f);
    unsigned r = (u + 0x7fffu + ((u >> 16) & 1u)) >> 16;
    return (short)r;
}

// two-axis bank swizzle: spreads both row and kg across bank quads
__device__ __forceinline__ int swz8(int row) { return (row & 7) ^ ((row & 3) << 1); }

// ---- stage 64 rows x 512B into LDS (linear dest, inverse-swizzled source) ----
__device__ __forceinline__ void stage64(const char* g0, size_t gstrideB, int kOffB, char* lds) {
    int tid = threadIdx.x;
#pragma unroll
    for (int it = 0; it < 8; ++it) {
        int chunk = it * 256 + tid;          // 0..2047
        int row = chunk >> 5;
        int g = chunk & 31;
        const char* src = g0 + (size_t)row * gstrideB + kOffB + ((g ^ swz8(row)) << 4);
        __builtin_amdgcn_global_load_lds((const __attribute__((address_space(1))) void*)src,
                                         (__attribute__((address_space(3))) void*)(lds + chunk * 16),
                                         16, 0, 0);
    }
}
__device__ __forceinline__ bf16x8 lds_frag(const char* lds, int row, int col16) {
    return *(const bf16x8*)(lds + row * 512 + ((col16 ^ swz8(row)) << 4));
}
// per-wave 16Mx64N x K=256 from staged [64][512B] tiles
__device__ __forceinline__ void mma_tile(const char* smA, const char* smB,
                                         int wave, int ln, int kg, f32x4 acc[4]) {
#pragma unroll
    for (int ks = 0; ks < 8; ++ks) {
        bf16x8 a = lds_frag(smA, wave * 16 + ln, ks * 4 + kg);
#pragma unroll
        for (int nf = 0; nf < 4; ++nf) {
            bf16x8 b = lds_frag(smB, nf * 16 + ln, ks * 4 + kg);
            acc[nf] = __builtin_amdgcn_mfma_f32_16x16x32_bf16(a, b, acc[nf], 0, 0, 0);
        }
    }
}

// ---- 128-row x 256B-half tile helpers (fc) ----
__device__ __forceinline__ bf16x8 frag128(const char* lds, int row, int gl) {
    return *(const bf16x8*)(lds + row * 256 + ((gl ^ swz8(row)) << 4));
}

// ---------------- fused setup (vectorized) ----------------
__global__ void k_setup(const float* __restrict__ fcw, const float* __restrict__ whh0,
                        const float* __restrict__ wih1, const float* __restrict__ whh1,
                        const float* __restrict__ phw, const float* __restrict__ pcw,
                        const float* __restrict__ wih0, const float* __restrict__ b1,
                        short* __restrict__ fcwbf, short* __restrict__ whh0i, short* __restrict__ w1i,
                        float* __restrict__ projhT, float* __restrict__ projcT,
                        float* __restrict__ ctxT, float* __restrict__ xT, float* __restrict__ b1i) {
    int bid = blockIdx.x, tid = threadIdx.x;
    if (bid < 2000) {                      // fcw cast (2,048,000)
        int i = (bid * 256 + tid) * 4;
        float4 v = *(const float4*)&fcw[i];
        short4 o = { f2b(v.x), f2b(v.y), f2b(v.z), f2b(v.w) };
        *(short4*)&fcwbf[i] = o;
        return;
    }
    bid -= 2000;
    if (bid < 256) {                       // whh0i gate-interleave (262,144)
        int i = (bid * 256 + tid) * 4;
        int gp = i >> 8, k = i & 255;
        float4 v = *(const float4*)&whh0[(size_t)((gp & 3) * 256 + (gp >> 2)) * 256 + k];
        short4 o = { f2b(v.x), f2b(v.y), f2b(v.z), f2b(v.w) };
        *(short4*)&whh0i[i] = o;
        return;
    }
    bid -= 256;
    if (bid < 512) {                       // w1i pack+interleave (524,288)
        int i = (bid * 256 + tid) * 4;
        int gp = i >> 9, k = i & 511;
        int g = (gp & 3) * 256 + (gp >> 2);
        const float* src = (k < 256) ? &wih1[(size_t)g * 256 + k] : &whh1[(size_t)g * 256 + (k - 256)];
        float4 v = *(const float4*)src;
        short4 o = { f2b(v.x), f2b(v.y), f2b(v.z), f2b(v.w) };
        *(short4*)&w1i[i] = o;
        return;
    }
    bid -= 512;
    if (bid < 128) {                       // projhT (131,072)
        int i = (bid * 256 + tid) * 4;
        int k = i >> 8, r = i & 255;
        float4 o = { phw[(size_t)r * ENC + k], phw[(size_t)(r + 1) * ENC + k],
                     phw[(size_t)(r + 2) * ENC + k], phw[(size_t)(r + 3) * ENC + k] };
        *(float4*)&projhT[i] = o;
        return;
    }
    bid -= 128;
    if (bid < 128) {                       // projcT
        int i = (bid * 256 + tid) * 4;
        int k = i >> 8, r = i & 255;
        float4 o = { pcw[(size_t)r * ENC + k], pcw[(size_t)(r + 1) * ENC + k],
                     pcw[(size_t)(r + 2) * ENC + k], pcw[(size_t)(r + 3) * ENC + k] };
        *(float4*)&projcT[i] = o;
        return;
    }
    bid -= 128;
    if (bid < 512) {                       // wih0 split (524,288)
        int i = (bid * 256 + tid) * 4;
        int g = i >> 9, k = i & 511;
        float4 v = *(const float4*)&wih0[i];
        float* base = (k < 256) ? &ctxT[(size_t)k * G4 + g] : &xT[(size_t)(k - 256) * G4 + g];
        base[0] = v.x; base[G4] = v.y; base[2 * G4] = v.z; base[3 * G4] = v.w;
        return;
    }
    bid -= 512;
    if (bid < 1) {                          // b1i (1024)
        float4 o = { b1[tid], b1[256 + tid], b1[512 + tid], b1[768 + tid] };
        *(float4*)&b1i[tid * 4] = o;
        return;
    }
}

// ---------------- h0/c0 ----------------
__global__ void k_init_state(const float* __restrict__ enc, const float* __restrict__ phT,
                             const float* __restrict__ phb, const float* __restrict__ pcT,
                             const float* __restrict__ pcb, float* __restrict__ h0, float* __restrict__ c0) {
    __shared__ float eo[ENC];
    int bi = blockIdx.x;
    int b = bi / T1, i = bi % T1;
    int j = threadIdx.x;
    for (int e = j; e < ENC; e += 256) eo[e] = enc[(size_t)(i * B + b) * ENC + e];
    __syncthreads();
    float ha = phb[j], ca = pcb[j];
    for (int e = 0; e < ENC; ++e) {
        float x = eo[e];
        ha += x * phT[(size_t)e * H + j];
        ca += x * pcT[(size_t)e * H + j];
    }
    h0[(size_t)bi * H + j] = ha;
    c0[(size_t)bi * H + j] = ca;
}

// ---------------- fused init ----------------
__global__ void k_init2(const int* __restrict__ y, const float* __restrict__ embed, const float* __restrict__ se,
                        const float* __restrict__ h0, const float* __restrict__ c0,
                        const float* __restrict__ ctxT, const float* __restrict__ xT,
                        const float* __restrict__ b0,
                        float* __restrict__ c1, float* __restrict__ c2,
                        short* __restrict__ hcA, short* __restrict__ hcB,
                        float* __restrict__ pre_ctxi, float* __restrict__ pre_xi) {
    __shared__ float sb[256];
    int bid = blockIdx.x, j = threadIdx.x;
    if (bid < NCELL) {
        int cell = bid, bi = cell / T21;
        c1[(size_t)cell * H + j] = c0[(size_t)bi * H + j];
        c2[(size_t)cell * H + j] = 0.f;
        hcA[(size_t)cell * 512 + j] = f2b(h0[(size_t)bi * H + j]);  // h1_{-1}
        hcB[(size_t)cell * 512 + 256 + j] = 0;                      // h2_{-1}
        return;
    }
    bid -= NCELL;
    if (bid < 64) {
        int bi = bid;
        sb[j] = h0[(size_t)bi * H + j];
        __syncthreads();
        float a0 = b0[j], a1 = b0[256 + j], a2 = b0[512 + j], a3 = b0[768 + j];
        for (int k = 0; k < H; ++k) {
            float x = sb[k];
            const float* w = ctxT + (size_t)k * G4;
            a0 += x * w[j]; a1 += x * w[256 + j]; a2 += x * w[512 + j]; a3 += x * w[768 + j];
        }
        *(float4*)&pre_ctxi[(size_t)bi * G4 + 4 * j] = make_float4(a0, a1, a2, a3);
        return;
    }
    bid -= 64;
    int row = bid;                    // (s*B + b)*T21 + t
    int s = row / (B * T21), rem = row % (B * T21);
    int b = rem / T21, t = rem % T21;
    const float* src;
    if (s == 0) src = se;
    else { int tt = t + s - 1; if (tt > 15) tt = 15; src = embed + (size_t)y[b * T2 + tt] * E; }
    sb[j] = src[j];
    __syncthreads();
    float a0 = 0, a1 = 0, a2 = 0, a3 = 0;
    for (int k = 0; k < E; ++k) {
        float x = sb[k];
        const float* w = xT + (size_t)k * G4;
        a0 += x * w[j]; a1 += x * w[256 + j]; a2 += x * w[512 + j]; a3 += x * w[768 + j];
    }
    *(float4*)&pre_xi[(size_t)row * G4 + 4 * j] = make_float4(a0, a1, a2, a3);
}

// ---------------- LSTM bodies: LDS-staged 64Mx64N tile ----------------
__device__ __forceinline__ void lstm0_body(int step, int l, char* smA, char* smB,
        const short* __restrict__ IN, const short* __restrict__ whh0i,
        const float* __restrict__ pre_ctxi, const float* __restrict__ pre_xi,
        float* __restrict__ c1, short* __restrict__ OUT) {
    int tid = threadIdx.x;
    int wave = tid >> 6, lane = tid & 63, ln = lane & 15, kg = lane >> 4;
    int mb = l >> 4, nb = l & 15;
    int m0 = mb * 64, n0 = nb * 64;
    stage64((const char*)(IN + (size_t)m0 * 512), 1024, 0, smA);      // h1_prev cols 0-255
    stage64((const char*)(whh0i + (size_t)n0 * 256), 512, 0, smB);
    __syncthreads();
    f32x4 acc[4] = {};
    mma_tile(smA, smB, wave, ln, kg, acc);
    __syncthreads();
    float* sg = (float*)smA;
#pragma unroll
    for (int nf = 0; nf < 4; ++nf)
#pragma unroll
        for (int r = 0; r < 4; ++r)
            sg[(wave * 16 + kg * 4 + r) * 68 + nf * 16 + ln] = acc[nf][r];
    __syncthreads();
    int jlo = nb * 16;
#pragma unroll
    for (int q2 = 0; q2 < 4; ++q2) {
        int item = q2 * 256 + tid;
        int c = item >> 4, jj = item & 15;
        int cell = m0 + c;
        int j = jlo + jj;
        float4 g = *(float4*)&sg[c * 68 + 4 * jj];
        int bi = cell / T21;
        int bb = bi >> 4;
        int t = cell % T21;
        int prow = (step * B + bb) * T21 + t;
        float4 pc = *(const float4*)&pre_ctxi[(size_t)bi * G4 + 4 * j];
        float4 px = *(const float4*)&pre_xi[(size_t)prow * G4 + 4 * j];
        float ig = g.x + pc.x + px.x, fg = g.y + pc.y + px.y;
        float gg = g.z + pc.z + px.z, og = g.w + pc.w + px.w;
        float cold = c1[(size_t)cell * H + j];
        float cn = sigm(fg) * cold + sigm(ig) * ftanh(gg);
        float hn = sigm(og) * ftanh(cn);
        c1[(size_t)cell * H + j] = cn;
        OUT[(size_t)cell * 512 + j] = f2b(hn);
    }
}

__device__ __forceinline__ void lstm1_body(int l, char* smA, char* smB,
        const short* __restrict__ IN, const short* __restrict__ w1i,
        const float* __restrict__ b1i, float* __restrict__ c2,
        short* __restrict__ slab, short* __restrict__ OUT) {
    int tid = threadIdx.x;
    int wave = tid >> 6, lane = tid & 63, ln = lane & 15, kg = lane >> 4;
    int mb = l >> 4, nb = l & 15;
    int m0 = mb * 64, n0 = nb * 64;
    f32x4 acc[4] = {};
#pragma unroll
    for (int kh = 0; kh < 2; ++kh) {
        if (kh) __syncthreads();
        stage64((const char*)(IN + (size_t)m0 * 512), 1024, kh * 512, smA);
        stage64((const char*)(w1i + (size_t)n0 * 512), 1024, kh * 512, smB);
        __syncthreads();
        mma_tile(smA, smB, wave, ln, kg, acc);
    }
    __syncthreads();
    float* sg = (float*)smA;
#pragma unroll
    for (int nf = 0; nf < 4; ++nf)
#pragma unroll
        for (int r = 0; r < 4; ++r)
            sg[(wave * 16 + kg * 4 + r) * 68 + nf * 16 + ln] = acc[nf][r];
    __syncthreads();
    int jlo = nb * 16;
#pragma unroll
    for (int q2 = 0; q2 < 4; ++q2) {
        int item = q2 * 256 + tid;
        int c = item >> 4, jj = item & 15;
        int cell = m0 + c;
        int j = jlo + jj;
        float4 g = *(float4*)&sg[c * 68 + 4 * jj];
        float4 bv = *(const float4*)&b1i[4 * j];
        float ig = g.x + bv.x, fg = g.y + bv.y, gg = g.z + bv.z, og = g.w + bv.w;
        float cold = c2[(size_t)cell * H + j];
        float cn = sigm(fg) * cold + sigm(ig) * ftanh(gg);
        float hn = sigm(og) * ftanh(cn);
        c2[(size_t)cell * H + j] = cn;
        short hb = f2b(hn);
        slab[(size_t)cell * 256 + j] = hb;
        OUT[(size_t)cell * 512 + 256 + j] = hb;
    }
}

// merged [L1_s || L0_{s+1}]
__global__ __launch_bounds__(256, 2) void k_lstm(int s, int n_l1,
        const short* __restrict__ IN, short* __restrict__ OUT, short* __restrict__ slab,
        const short* __restrict__ whh0i, const short* __restrict__ w1i,
        const float* __restrict__ pre_ctxi, const float* __restrict__ pre_xi,
        const float* __restrict__ b1i, float* __restrict__ c1, float* __restrict__ c2) {
    __shared__ char smem[65536];
    char* smA = smem;
    char* smB = smem + 32768;
    int bx = blockIdx.x;
    if (bx < n_l1) lstm1_body(bx, smA, smB, IN, w1i, b1i, c2, slab, OUT);
    else lstm0_body(s + 1, bx - n_l1, smA, smB, IN, whh0i, pre_ctxi, pre_xi, c1, OUT);
}

// ---------------- fc: 128x128 tile, K=256 in 2 staged halves ----------------
__global__ __launch_bounds__(256, 2) void k_fc(const short* __restrict__ h2base, const short* __restrict__ Wv,
        const float* __restrict__ fcb, float* __restrict__ psum) {
    __shared__ char smem[65536];
    char* smA = smem;            // [128][256B] half-tile
    char* smB = smem + 32768;
    int bx = blockIdx.x;
    int xcd = bx & 7, idx = bx >> 3;
    int q = NFCT >> 3, r = NFCT & 7;
    int tl = xcd * q + (xcd < r ? xcd : r) + idx;
    int nb = tl / NTM, mb = tl % NTM;     // nb-major: XCD keeps B-band L2-resident
    int m0 = mb * 128, n0 = nb * 128;
    int tid = threadIdx.x;
    int wave = tid >> 6, lane = tid & 63, ln = lane & 15, kg = lane >> 4;
    int wm = wave >> 1, wn = wave & 1;
    f32x4 acc[4][4] = {};
#pragma unroll
    for (int kh = 0; kh < 2; ++kh) {
        if (kh) __syncthreads();
        // stage A half: rows m0..m0+127 (padded alloc), linear dest + inverse-swizzled src
#pragma unroll
        for (int it = 0; it < 8; ++it) {
            int chunk = it * 256 + tid;       // 0..2047
            int row = chunk >> 4;
            int g = chunk & 15;
            const char* src = (const char*)(h2base + (size_t)(m0 + row) * 256)
                              + kh * 256 + ((g ^ swz8(row)) << 4);
            __builtin_amdgcn_global_load_lds((const __attribute__((address_space(1))) void*)src,
                                             (__attribute__((address_space(3))) void*)(smA + chunk * 16),
                                             16, 0, 0);
        }
        // stage B half: vocab rows n0..n0+127 clamped to V-1 (pad cols killed by fbn)
#pragma unroll
        for (int it = 0; it < 8; ++it) {
            int chunk = it * 256 + tid;
            int row = chunk >> 4;
            int g = chunk & 15;
            int grow = n0 + row; if (grow > V - 1) grow = V - 1;
            const char* src = (const char*)(Wv + (size_t)grow * 256)
                              + kh * 256 + ((g ^ swz8(row)) << 4);
            __builtin_amdgcn_global_load_lds((const __attribute__((address_space(1))) void*)src,
                                             (__attribute__((address_space(3))) void*)(smB + chunk * 16),
                                             16, 0, 0);
        }
        __syncthreads();
#pragma unroll
        for (int ks = 0; ks < 4; ++ks) {
            bf16x8 a[4], b[4];
#pragma unroll
            for (int mf = 0; mf < 4; ++mf) a[mf] = frag128(smA, wm * 64 + mf * 16 + ln, ks * 4 + kg);
#pragma unroll
            for (int nf = 0; nf < 4; ++nf) b[nf] = frag128(smB, wn * 64 + nf * 16 + ln, ks * 4 + kg);
#pragma unroll
            for (int mf = 0; mf < 4; ++mf)
#pragma unroll
                for (int nf = 0; nf < 4; ++nf)
                    acc[mf][nf] = __builtin_amdgcn_mfma_f32_16x16x32_bf16(a[mf], b[nf], acc[mf][nf], 0, 0, 0);
        }
    }
    // epilogue: per-row exp-sums over this block's 64-col slice (wn)
    float rs[4][4];
#pragma unroll
    for (int mf = 0; mf < 4; ++mf)
#pragma unroll
        for (int r2 = 0; r2 < 4; ++r2) rs[mf][r2] = 0.f;
#pragma unroll
    for (int nf = 0; nf < 4; ++nf) {
        int col = n0 + wn * 64 + nf * 16 + ln;
        float fbn = (col < V) ? fcb[col] : NEGV;
#pragma unroll
        for (int mf = 0; mf < 4; ++mf)
#pragma unroll
            for (int r2 = 0; r2 < 4; ++r2)
                rs[mf][r2] += __expf(acc[mf][nf][r2] + fbn);
    }
#pragma unroll
    for (int mask = 1; mask < 16; mask <<= 1)
#pragma unroll
        for (int mf = 0; mf < 4; ++mf)
#pragma unroll
            for (int r2 = 0; r2 < 4; ++r2)
                rs[mf][r2] += __shfl_xor(rs[mf][r2], mask);
    if (ln == 0) {
#pragma unroll
        for (int mf = 0; mf < 4; ++mf)
#pragma unroll
            for (int r2 = 0; r2 < 4; ++r2)
                psum[(size_t)(nb * 2 + wn) * MP + m0 + wm * 64 + mf * 16 + kg * 4 + r2] = rs[mf][r2];
    }
}

// ---------------- combine: tgt/EOS dots + sum of 126 psum partials ----------------
__global__ void k_combine(const short* __restrict__ h2all, const short* __restrict__ Wv,
        const float* __restrict__ fcb, const int* __restrict__ y,
        const float* __restrict__ psum, float* __restrict__ sel, float* __restrict__ eosp) {
    int cb = blockIdx.x;                 // s*17 + blk
    int s = cb / 17, blk = cb % 17;
    int tid = threadIdx.x;
    int cl = tid >> 2, q = tid & 3;
    int cell = blk * 64 + cl;
    int b = cell / (T1 * T21);
    int t = cell % T21;
    int tv = 0;
    if (s < SEG) { int tt = t + s; if (tt > 15) tt = 15; tv = y[b * T2 + tt]; }
    const short* hp = h2all + (size_t)(s + 1) * NCELL * 256 + (size_t)cell * 256 + q * 64;
    const short* w1 = Wv + (size_t)tv * 256 + q * 64;
    const short* w2 = Wv + (size_t)EOS * 256 + q * 64;
    float d1 = 0.f, d2 = 0.f;
#pragma unroll
    for (int u = 0; u < 8; ++u) {
        bf16x8 av  = *(const bf16x8*)(hp + u * 8);
        bf16x8 wv1 = *(const bf16x8*)(w1 + u * 8);
        bf16x8 wv2 = *(const bf16x8*)(w2 + u * 8);
#pragma unroll
        for (int e = 0; e < 8; ++e) {
            float a = b2f(av[e]);
            d1 += a * b2f(wv1[e]);
            d2 += a * b2f(wv2[e]);
        }
    }
    d1 += __shfl_xor(d1, 1); d1 += __shfl_xor(d1, 2);
    d2 += __shfl_xor(d2, 1); d2 += __shfl_xor(d2, 2);
    int col = s * NCELL + cell;
    float ss = 0.f;
    for (int v2 = q * 32; v2 < q * 32 + 32 && v2 < NPART; ++v2)
        ss += psum[(size_t)v2 * MP + col];
    ss += __shfl_xor(ss, 1); ss += __shfl_xor(ss, 2);
    if (q == 0) {
        float lse = __logf(ss);
        sel[s * NCELL + cell]  = d1 + fcb[tv]  - lse;
        eosp[s * NCELL + cell] = d2 + fcb[EOS] - lse;
    }
}

// ---------------- final DP, fully LDS-resident ----------------
__global__ void k_dp(const float* __restrict__ sel, const float* __restrict__ eosp, float* __restrict__ out) {
    __shared__ float row[SEG + 1][NCELL];
    __shared__ float alpha[B][T21];
    int tid = threadIdx.x;
    for (int c = tid; c < NCELL; c += 256) {
        float cum = 0.f;
        row[0][c] = eosp[c];
#pragma unroll
        for (int j = 1; j <= SEG; ++j) {
            cum += sel[(j - 1) * NCELL + c];
            row[j][c] = cum + eosp[j * NCELL + c];
        }
    }
    int b = tid / T21, t = tid % T21;
    bool act = tid < B * T21;
    if (act) alpha[b][t] = (t == 0) ? 0.f : NEGV;
    __syncthreads();
    for (int i = 0; i < T1; ++i) {
        float val = NEGV;
        if (act) {
            float terms[SEG + 1];
            float mx = -3.4e38f;
            int cnt2 = 0;
            for (int j = 0; j <= SEG && j <= t; ++j) {
                int cell = (b * T1 + i) * T21 + (t - j);
                float term = alpha[b][t - j] + row[j][cell];
                terms[cnt2++] = term;
                mx = fmaxf(mx, term);
            }
            float ssum = 0.f;
            for (int k2 = 0; k2 < cnt2; ++k2) ssum += __expf(terms[k2] - mx);
            val = mx + __logf(ssum);
        }
        __syncthreads();
        if (act) alpha[b][t] = val;
        __syncthreads();
    }
    if (act && t == T2) out[b] = alpha[b][T2];
}

extern "C" void kernel_launch(void* const* d_in, const int* in_sizes, int n_in,
                              void* d_out, int out_size, void* d_ws, size_t ws_size,
                              hipStream_t stream) {
    const int*   y     = (const int*)d_in[0];
    const float* enc   = (const float*)d_in[1];
    const float* embed = (const float*)d_in[2];
    const float* se    = (const float*)d_in[3];
    const float* phw   = (const float*)d_in[4];
    const float* phb   = (const float*)d_in[5];
    const float* pcw   = (const float*)d_in[6];
    const float* pcb   = (const float*)d_in[7];
    const float* wih0  = (const float*)d_in[8];
    const float* whh0  = (const float*)d_in[9];
    const float* b0    = (const float*)d_in[10];
    const float* wih1  = (const float*)d_in[11];
    const float* whh1  = (const float*)d_in[12];
    const float* b1    = (const float*)d_in[13];
    const float* fcw   = (const float*)d_in[14];
    const float* fcb   = (const float*)d_in[15];

    float* ws = (float*)d_ws;
    size_t off = 0;
    auto alloc = [&](size_t n) { float* p = ws + off; off += n; return p; };
    float* projhT   = alloc((size_t)ENC * H);
    float* projcT   = alloc((size_t)ENC * H);
    float* ctxT     = alloc((size_t)H * G4);
    float* xT       = alloc((size_t)E * G4);
    float* h0       = alloc((size_t)B * T1 * H);
    float* c0       = alloc((size_t)B * T1 * H);
    float* pre_ctxi = alloc((size_t)B * T1 * G4);
    float* pre_xi   = alloc((size_t)(SEG + 1) * B * T21 * G4);
    float* c1       = alloc((size_t)NCELL * H);
    float* c2       = alloc((size_t)NCELL * H);
    float* b1i      = alloc((size_t)G4);
    float* selbuf   = alloc((size_t)(SEG + 1) * NCELL);
    float* eospbuf  = alloc((size_t)(SEG + 1) * NCELL);
    float* psum     = alloc((size_t)NPART * MP);
    short* hc0      = (short*)alloc((size_t)NCELL * 512 / 2);
    short* hc1      = (short*)alloc((size_t)NCELL * 512 / 2);
    short* h2all    = (short*)alloc(((size_t)6 * NCELL + 64) * 256 / 2);  // +64 pad rows
    short* whh0i    = (short*)alloc((size_t)G4 * 256 / 2);
    short* w1i      = (short*)alloc((size_t)G4 * 512 / 2);
    short* fcwbf    = (short*)alloc((size_t)V * H / 2);

    hipLaunchKernelGGL(k_setup, dim3(3537), dim3(256), 0, stream,
                       fcw, whh0, wih1, whh1, phw, pcw, wih0, b1,
                       fcwbf, whh0i, w1i, projhT, projcT, ctxT, xT, b1i);
    hipLaunchKernelGGL(k_init_state, dim3(B * T1), dim3(256), 0, stream,
                       enc, projhT, phb, projcT, pcb, h0, c0);
    hipLaunchKernelGGL(k_init2, dim3(NCELL + 64 + (SEG + 1) * B * T21), dim3(256), 0, stream,
                       y, embed, se, h0, c0, ctxT, xT, b0, c1, c2, hc0, hc1,
                       pre_ctxi, pre_xi);

    // H_{-1}=hc0, H_0=hc1, H_1=hc0, ... (H_s = hcb[(s+1)&1])
    short* hcb[2] = { hc0, hc1 };
    hipLaunchKernelGGL(k_lstm, dim3(NL), dim3(256), 0, stream,
                       -1, 0, hcb[0], hcb[1], h2all,
                       whh0i, w1i, pre_ctxi, pre_xi, b1i, c1, c2);
    for (int s = 0; s < SEG; ++s) {
        hipLaunchKernelGGL(k_lstm, dim3(2 * NL), dim3(256), 0, stream,
                           s, NL, hcb[(s + 1) & 1], hcb[s & 1],
                           h2all + (size_t)(s + 1) * NCELL * 256,
                           whh0i, w1i, pre_ctxi, pre_xi, b1i, c1, c2);
    }
    hipLaunchKernelGGL(k_lstm, dim3(NL), dim3(256), 0, stream,
                       4, NL, hcb[1], hcb[0],
                       h2all + (size_t)5 * NCELL * 256,
                       whh0i, w1i, pre_ctxi, pre_xi, b1i, c1, c2);

    hipLaunchKernelGGL(k_fc, dim3(NFCT), dim3(256), 0, stream,
                       h2all + (size_t)NCELL * 256, fcwbf, fcb, psum);
    hipLaunchKernelGGL(k_combine, dim3(85), dim3(256), 0, stream,
                       h2all, fcwbf, fcb, y, psum, selbuf, eospbuf);
    hipLaunchKernelGGL(k_dp, dim3(1), dim3(256), 0, stream, selbuf, eospbuf, (float*)d_out);
}